// Round 1
// baseline (14457.347 us; speedup 1.0000x reference)
//
#include <hip/hip_runtime.h>
#include <hip/hip_bf16.h>

#define NN 100000
#define NE 1600000
#define F_IN 512
#define HID 128
#define C_OUT 64
#define L_LAYERS 64

// ---------------- preprocessing ----------------

__global__ void count_deg(const int* __restrict__ dst, int* __restrict__ cnt) {
    int e = blockIdx.x * blockDim.x + threadIdx.x;
    if (e < NE) atomicAdd(&cnt[dst[e]], 1);
}

__global__ void compute_dinv(const int* __restrict__ cnt, float* __restrict__ dinv) {
    int n = blockIdx.x * blockDim.x + threadIdx.x;
    if (n < NN) dinv[n] = rsqrtf((float)cnt[n] + 1.0f);
}

// single-block exclusive scan of cnt[0..NN) -> row_ptr[0..NN], 256 threads, 1024/round
__global__ void scan_rowptr(const int* __restrict__ cnt, int* __restrict__ row_ptr) {
    __shared__ int sdata[256];
    __shared__ int carry_s;
    int tid = threadIdx.x;
    if (tid == 0) carry_s = 0;
    __syncthreads();
    for (int base = 0; base < NN; base += 1024) {
        int v[4];
        int idx0 = base + tid * 4;
#pragma unroll
        for (int i = 0; i < 4; ++i) {
            int idx = idx0 + i;
            v[i] = (idx < NN) ? cnt[idx] : 0;
        }
        int s = v[0] + v[1] + v[2] + v[3];
        sdata[tid] = s;
        __syncthreads();
        int x = s;
        for (int off = 1; off < 256; off <<= 1) {
            int y = (tid >= off) ? sdata[tid - off] : 0;
            __syncthreads();
            x += y;
            sdata[tid] = x;
            __syncthreads();
        }
        int excl = x - s + carry_s;
        int run = excl;
#pragma unroll
        for (int i = 0; i < 4; ++i) {
            int idx = idx0 + i;
            if (idx < NN) row_ptr[idx] = run;
            run += v[i];
        }
        __syncthreads();
        if (tid == 255) carry_s += x;
        __syncthreads();
    }
    if (tid == 0) row_ptr[NN] = carry_s;
}

__global__ void scatter_csr(const int* __restrict__ src, const int* __restrict__ dst,
                            const float* __restrict__ dinv, int* __restrict__ fill,
                            int* __restrict__ csr_src, float* __restrict__ csr_w) {
    int e = blockIdx.x * blockDim.x + threadIdx.x;
    if (e >= NE) return;
    int s = src[e], d = dst[e];
    int pos = atomicAdd(&fill[d], 1);
    csr_src[pos] = s;
    csr_w[pos] = dinv[s] * dinv[d];
}

// ---------------- x0 = relu(X @ W_in + b) ----------------
// BM=64, BN=128, BK=32; 256 threads as 16x16; each thread 4 rows x 8 cols
__global__ __launch_bounds__(256) void gemm_x0(const float* __restrict__ X,
                                               const float* __restrict__ W,
                                               const float* __restrict__ b,
                                               float* __restrict__ X0) {
    __shared__ float Xs[64][33];
    __shared__ float Ws[32][128];
    int tid = threadIdx.x;
    int tx = tid & 15, ty = tid >> 4;
    int row0 = blockIdx.x * 64;
    float acc[4][8] = {};
    for (int k0 = 0; k0 < F_IN; k0 += 32) {
        // load X tile 64x32: 512 float4, 2 per thread
#pragma unroll
        for (int i = 0; i < 2; ++i) {
            int idx = tid + i * 256;
            int r = idx >> 3, c4 = idx & 7;
            int row = row0 + r;
            float4 v = make_float4(0.f, 0.f, 0.f, 0.f);
            if (row < NN) v = *(const float4*)&X[row * F_IN + k0 + c4 * 4];
            Xs[r][c4 * 4 + 0] = v.x; Xs[r][c4 * 4 + 1] = v.y;
            Xs[r][c4 * 4 + 2] = v.z; Xs[r][c4 * 4 + 3] = v.w;
        }
        // load W tile 32x128: 1024 float4, 4 per thread
#pragma unroll
        for (int i = 0; i < 4; ++i) {
            int idx = tid + i * 256;
            int r = idx >> 5, c4 = idx & 31;
            *(float4*)&Ws[r][c4 * 4] = *(const float4*)&W[(k0 + r) * HID + c4 * 4];
        }
        __syncthreads();
#pragma unroll
        for (int k = 0; k < 32; ++k) {
            float a[4], w[8];
#pragma unroll
            for (int i = 0; i < 4; ++i) a[i] = Xs[ty * 4 + i][k];
#pragma unroll
            for (int j = 0; j < 8; ++j) w[j] = Ws[k][tx * 8 + j];
#pragma unroll
            for (int i = 0; i < 4; ++i)
#pragma unroll
                for (int j = 0; j < 8; ++j) acc[i][j] = fmaf(a[i], w[j], acc[i][j]);
        }
        __syncthreads();
    }
#pragma unroll
    for (int i = 0; i < 4; ++i) {
        int row = row0 + ty * 4 + i;
        if (row >= NN) continue;
#pragma unroll
        for (int j = 0; j < 8; ++j) {
            int c = tx * 8 + j;
            float v = acc[i][j] + b[c];
            X0[row * HID + c] = fmaxf(v, 0.f);
        }
    }
}

// ---------------- spmm + residual: T = 0.9*(A_hat h) + 0.1*x0 ----------------
__global__ __launch_bounds__(128) void spmm_kernel(const float* __restrict__ H,
                                                   const float* __restrict__ X0,
                                                   const float* __restrict__ dinv,
                                                   const int* __restrict__ row_ptr,
                                                   const int* __restrict__ csr_src,
                                                   const float* __restrict__ csr_w,
                                                   float* __restrict__ T) {
    int n = blockIdx.x;
    int tid = threadIdx.x;
    float dv = dinv[n];
    float acc = dv * dv * H[n * HID + tid];
    int e0 = row_ptr[n], e1 = row_ptr[n + 1];
    int e = e0;
    for (; e + 3 < e1; e += 4) {
        int s0 = csr_src[e], s1 = csr_src[e + 1], s2 = csr_src[e + 2], s3 = csr_src[e + 3];
        float w0 = csr_w[e], w1 = csr_w[e + 1], w2 = csr_w[e + 2], w3 = csr_w[e + 3];
        float h0 = H[s0 * HID + tid];
        float h1 = H[s1 * HID + tid];
        float h2 = H[s2 * HID + tid];
        float h3 = H[s3 * HID + tid];
        acc = fmaf(w0, h0, acc);
        acc = fmaf(w1, h1, acc);
        acc = fmaf(w2, h2, acc);
        acc = fmaf(w3, h3, acc);
    }
    for (; e < e1; ++e) {
        int s = csr_src[e];
        acc = fmaf(csr_w[e], H[s * HID + tid], acc);
    }
    T[n * HID + tid] = 0.9f * acc + 0.1f * X0[n * HID + tid];
}

// ---------------- layer gemm: H = relu((1-beta)*T + beta*(T@W)) ----------------
// BM=64, BN=128, K=128 (BK=32); T tile kept fully in LDS for epilogue
__global__ __launch_bounds__(256) void layer_gemm(const float* __restrict__ T,
                                                  const float* __restrict__ W,
                                                  float beta, float* __restrict__ Hout) {
    __shared__ float Ts[64][129];
    __shared__ float Ws[32][128];
    int tid = threadIdx.x;
    int tx = tid & 15, ty = tid >> 4;
    int row0 = blockIdx.x * 64;
    // load full T tile 64x128: 2048 float4, 8 per thread
#pragma unroll
    for (int i = 0; i < 8; ++i) {
        int idx = tid + i * 256;
        int r = idx >> 5, c4 = idx & 31;
        int row = row0 + r;
        float4 v = make_float4(0.f, 0.f, 0.f, 0.f);
        if (row < NN) v = *(const float4*)&T[row * HID + c4 * 4];
        Ts[r][c4 * 4 + 0] = v.x; Ts[r][c4 * 4 + 1] = v.y;
        Ts[r][c4 * 4 + 2] = v.z; Ts[r][c4 * 4 + 3] = v.w;
    }
    float acc[4][8] = {};
    for (int k0 = 0; k0 < HID; k0 += 32) {
#pragma unroll
        for (int i = 0; i < 4; ++i) {
            int idx = tid + i * 256;
            int r = idx >> 5, c4 = idx & 31;
            *(float4*)&Ws[r][c4 * 4] = *(const float4*)&W[(k0 + r) * HID + c4 * 4];
        }
        __syncthreads();
#pragma unroll
        for (int k = 0; k < 32; ++k) {
            float a[4], w[8];
#pragma unroll
            for (int i = 0; i < 4; ++i) a[i] = Ts[ty * 4 + i][k0 + k];
#pragma unroll
            for (int j = 0; j < 8; ++j) w[j] = Ws[k][tx * 8 + j];
#pragma unroll
            for (int i = 0; i < 4; ++i)
#pragma unroll
                for (int j = 0; j < 8; ++j) acc[i][j] = fmaf(a[i], w[j], acc[i][j]);
        }
        __syncthreads();
    }
    float omb = 1.0f - beta;
#pragma unroll
    for (int i = 0; i < 4; ++i) {
        int row = row0 + ty * 4 + i;
        if (row >= NN) continue;
#pragma unroll
        for (int j = 0; j < 8; ++j) {
            int c = tx * 8 + j;
            float tv = Ts[ty * 4 + i][c];
            float v = omb * tv + beta * acc[i][j];
            Hout[row * HID + c] = fmaxf(v, 0.f);
        }
    }
}

// ---------------- final: z copy + log_softmax(z @ W_out + b_out) ----------------
__global__ __launch_bounds__(64) void final_kernel(const float* __restrict__ Z,
                                                   const float* __restrict__ Wout,
                                                   const float* __restrict__ bout,
                                                   float* __restrict__ out) {
    int n = blockIdx.x;
    int c = threadIdx.x;  // 64 threads = 1 wave
    float* zo = out;
    float* lo = out + (size_t)NN * HID;
    float logit = bout[c];
    for (int k = 0; k < HID; ++k) {
        logit = fmaf(Z[n * HID + k], Wout[k * C_OUT + c], logit);
    }
    zo[n * HID + c] = Z[n * HID + c];
    zo[n * HID + 64 + c] = Z[n * HID + 64 + c];
    float m = logit;
#pragma unroll
    for (int off = 32; off; off >>= 1) m = fmaxf(m, __shfl_xor(m, off));
    float ex = __expf(logit - m);
    float ssum = ex;
#pragma unroll
    for (int off = 32; off; off >>= 1) ssum += __shfl_xor(ssum, off);
    lo[n * C_OUT + c] = logit - m - logf(ssum);
}

extern "C" void kernel_launch(void* const* d_in, const int* in_sizes, int n_in,
                              void* d_out, int out_size, void* d_ws, size_t ws_size,
                              hipStream_t stream) {
    const float* x = (const float*)d_in[0];
    const int* ei = (const int*)d_in[1];
    const int* src = ei;
    const int* dst = ei + NE;
    const float* W_in = (const float*)d_in[2];
    const float* b_in = (const float*)d_in[3];
    const float* W_convs = (const float*)d_in[4];
    const float* W_out = (const float*)d_in[5];
    const float* b_out = (const float*)d_in[6];
    float* out = (float*)d_out;

    char* ws = (char*)d_ws;
    float* dinv = (float*)ws;            ws += (size_t)NN * 4;
    int* row_ptr = (int*)ws;             ws += (size_t)(NN + 4) * 4;
    int* fill = (int*)ws;                ws += (size_t)NN * 4;
    int* csr_src = (int*)ws;             ws += (size_t)NE * 4;
    float* csr_w = (float*)ws;           ws += (size_t)NE * 4;
    float* x0 = (float*)ws;              ws += (size_t)NN * HID * 4;
    float* hA = (float*)ws;              ws += (size_t)NN * HID * 4;  // t buffer
    float* hB = (float*)ws;              ws += (size_t)NN * HID * 4;  // h buffer

    hipMemsetAsync(fill, 0, (size_t)NN * 4, stream);
    count_deg<<<(NE + 255) / 256, 256, 0, stream>>>(dst, fill);
    compute_dinv<<<(NN + 255) / 256, 256, 0, stream>>>(fill, dinv);
    scan_rowptr<<<1, 256, 0, stream>>>(fill, row_ptr);
    hipMemcpyAsync(fill, row_ptr, (size_t)NN * 4, hipMemcpyDeviceToDevice, stream);
    scatter_csr<<<(NE + 255) / 256, 256, 0, stream>>>(src, dst, dinv, fill, csr_src, csr_w);

    int gemm_blocks = (NN + 63) / 64;
    gemm_x0<<<gemm_blocks, 256, 0, stream>>>(x, W_in, b_in, x0);

    for (int l = 0; l < L_LAYERS; ++l) {
        const float* h_in = (l == 0) ? x0 : hB;
        float beta = logf(0.5f / (float)(l + 1) + 1.0f);
        spmm_kernel<<<NN, 128, 0, stream>>>(h_in, x0, dinv, row_ptr, csr_src, csr_w, hA);
        layer_gemm<<<gemm_blocks, 256, 0, stream>>>(hA, W_convs + (size_t)l * HID * HID, beta, hB);
    }

    final_kernel<<<NN, 64, 0, stream>>>(hB, W_out, b_out, out);
}

// Round 2
// 10849.599 us; speedup vs baseline: 1.3325x; 1.3325x over previous
//
#include <hip/hip_runtime.h>
#include <hip/hip_bf16.h>

#define NN 100000
#define NE 1600000
#define F_IN 512
#define HID 128
#define C_OUT 64
#define L_LAYERS 64

using short8 = __attribute__((ext_vector_type(8))) short;
using f32x4  = __attribute__((ext_vector_type(4))) float;

__device__ __forceinline__ short f2bf(float f) {
    __hip_bfloat16 h = __float2bfloat16(f);
    return __builtin_bit_cast(short, h);
}
__device__ __forceinline__ float bflo(unsigned u) { return __uint_as_float(u << 16); }
__device__ __forceinline__ float bfhi(unsigned u) { return __uint_as_float(u & 0xffff0000u); }

// ---------------- preprocessing ----------------

__global__ void count_deg(const int* __restrict__ dst, int* __restrict__ cnt) {
    int e = blockIdx.x * blockDim.x + threadIdx.x;
    if (e < NE) atomicAdd(&cnt[dst[e]], 1);
}

__global__ void compute_dinv(const int* __restrict__ cnt, float* __restrict__ dinv) {
    int n = blockIdx.x * blockDim.x + threadIdx.x;
    if (n < NN) dinv[n] = rsqrtf((float)cnt[n] + 1.0f);
}

__global__ void scan_rowptr(const int* __restrict__ cnt, int* __restrict__ row_ptr) {
    __shared__ int sdata[256];
    __shared__ int carry_s;
    int tid = threadIdx.x;
    if (tid == 0) carry_s = 0;
    __syncthreads();
    for (int base = 0; base < NN; base += 1024) {
        int v[4];
        int idx0 = base + tid * 4;
#pragma unroll
        for (int i = 0; i < 4; ++i) {
            int idx = idx0 + i;
            v[i] = (idx < NN) ? cnt[idx] : 0;
        }
        int s = v[0] + v[1] + v[2] + v[3];
        sdata[tid] = s;
        __syncthreads();
        int x = s;
        for (int off = 1; off < 256; off <<= 1) {
            int y = (tid >= off) ? sdata[tid - off] : 0;
            __syncthreads();
            x += y;
            sdata[tid] = x;
            __syncthreads();
        }
        int excl = x - s + carry_s;
        int run = excl;
#pragma unroll
        for (int i = 0; i < 4; ++i) {
            int idx = idx0 + i;
            if (idx < NN) row_ptr[idx] = run;
            run += v[i];
        }
        __syncthreads();
        if (tid == 255) carry_s += x;
        __syncthreads();
    }
    if (tid == 0) row_ptr[NN] = carry_s;
}

__global__ void scatter_csr(const int* __restrict__ src, const int* __restrict__ dst,
                            const float* __restrict__ dinv, int* __restrict__ fill,
                            int* __restrict__ csr_src, float* __restrict__ csr_w) {
    int e = blockIdx.x * blockDim.x + threadIdx.x;
    if (e >= NE) return;
    int s = src[e], d = dst[e];
    int pos = atomicAdd(&fill[d], 1);
    csr_src[pos] = s;
    csr_w[pos] = dinv[s] * dinv[d];
}

// convert/transposed weights to bf16:
// blocks 0..63: WT[l][n][k] = bf16(W_convs[l][k][n])   (128x128)
// blocks 64..79: WinT[n][k] = bf16(W_in[k][n])          (128x512)
__global__ __launch_bounds__(256) void prep_wt(const float* __restrict__ Wc,
                                               const float* __restrict__ Win,
                                               __hip_bfloat16* __restrict__ WT,
                                               __hip_bfloat16* __restrict__ WinT) {
    int b = blockIdx.x, tid = threadIdx.x;
    if (b < 64) {
        const float* src = Wc + (size_t)b * HID * HID;
        __hip_bfloat16* dstp = WT + (size_t)b * HID * HID;
        for (int it = 0; it < 64; ++it) {
            int idx = it * 256 + tid;           // n*128 + k
            int n = idx >> 7, k = idx & 127;
            dstp[idx] = __float2bfloat16(src[k * HID + n]);
        }
    } else {
        int j = b - 64;
        for (int it = 0; it < 16; ++it) {
            int gid = j * 4096 + it * 256 + tid;  // n*512 + k
            int n = gid >> 9, k = gid & 511;
            WinT[gid] = __float2bfloat16(Win[k * HID + n]);
        }
    }
}

// ---------------- x0 = relu(X @ W_in + b), bf16 MFMA, output bf16 ----------------
__global__ __launch_bounds__(256) void gemm_x0_mfma(const float* __restrict__ X,
                                                    const __hip_bfloat16* __restrict__ WinT,
                                                    const float* __restrict__ bias,
                                                    __hip_bfloat16* __restrict__ X0b) {
    __shared__ short Xs[128 * 32];
    __shared__ short Ws[128 * 32];
    int tid = threadIdx.x;
    int w = tid >> 6, l = tid & 63, g = l >> 4, r = l & 15;
    int row0 = blockIdx.x * 128;
    f32x4 acc[2][8] = {};

    for (int kt = 0; kt < 16; ++kt) {
        int k0 = kt * 32;
#pragma unroll
        for (int i = 0; i < 2; ++i) {
            int id = i * 256 + tid;
            int rr = id >> 2, slot = id & 3;
            int grow = row0 + rr;
            float4 v0 = make_float4(0.f, 0.f, 0.f, 0.f), v1 = v0;
            if (grow < NN) {
                v0 = *(const float4*)&X[(size_t)grow * F_IN + k0 + slot * 8];
                v1 = *(const float4*)&X[(size_t)grow * F_IN + k0 + slot * 8 + 4];
            }
            short8 p;
            p[0] = f2bf(v0.x); p[1] = f2bf(v0.y); p[2] = f2bf(v0.z); p[3] = f2bf(v0.w);
            p[4] = f2bf(v1.x); p[5] = f2bf(v1.y); p[6] = f2bf(v1.z); p[7] = f2bf(v1.w);
            *(short8*)&Xs[rr * 32 + slot * 8] = p;
        }
#pragma unroll
        for (int i = 0; i < 2; ++i) {
            int id = i * 256 + tid;
            int nn = id >> 2, slot = id & 3;
            uint4 wv = *(const uint4*)&WinT[(size_t)nn * F_IN + k0 + slot * 8];
            *(uint4*)&Ws[nn * 32 + slot * 8] = wv;
        }
        __syncthreads();
        short8 a[2], bb[8];
#pragma unroll
        for (int m = 0; m < 2; ++m)
            a[m] = *(short8*)&Xs[(w * 32 + m * 16 + r) * 32 + g * 8];
#pragma unroll
        for (int n = 0; n < 8; ++n)
            bb[n] = *(short8*)&Ws[(n * 16 + r) * 32 + g * 8];
#pragma unroll
        for (int m = 0; m < 2; ++m)
#pragma unroll
            for (int n = 0; n < 8; ++n)
                acc[m][n] = __builtin_amdgcn_mfma_f32_16x16x32_bf16(a[m], bb[n], acc[m][n], 0, 0, 0);
        __syncthreads();
    }
#pragma unroll
    for (int m = 0; m < 2; ++m) {
#pragma unroll
        for (int n = 0; n < 8; ++n) {
            int col = n * 16 + r;
            float bv = bias[col];
#pragma unroll
            for (int q = 0; q < 4; ++q) {
                int row = row0 + w * 32 + m * 16 + g * 4 + q;
                if (row < NN) {
                    float v = fmaxf(acc[m][n][q] + bv, 0.f);
                    X0b[(size_t)row * HID + col] = __float2bfloat16(v);
                }
            }
        }
    }
}

// ---------------- spmm + residual: T = 0.9*(A_hat h) + 0.1*x0, bf16 gather, fp32 out ----------------
__global__ __launch_bounds__(256) void spmm_bf16(const unsigned* __restrict__ H2,
                                                 const unsigned* __restrict__ X02,
                                                 const float* __restrict__ dinv,
                                                 const int* __restrict__ row_ptr,
                                                 const int* __restrict__ csr_src,
                                                 const float* __restrict__ csr_w,
                                                 float* __restrict__ T) {
    int n = blockIdx.x * 4 + (threadIdx.x >> 6);
    if (n >= NN) return;
    int l = threadIdx.x & 63;
    float dv = dinv[n];
    unsigned hs = H2[(size_t)n * 64 + l];
    float sw = dv * dv;
    float a0 = sw * bflo(hs), a1 = sw * bfhi(hs);
    int e0 = row_ptr[n], e1 = row_ptr[n + 1];
    for (int base = e0; base < e1; base += 64) {
        int cnt = e1 - base; if (cnt > 64) cnt = 64;
        int idx = base + l;
        int   sv = (idx < e1) ? csr_src[idx] : 0;
        float wv = (idx < e1) ? csr_w[idx] : 0.f;
        for (int j = 0; j < cnt; ++j) {
            int s = __shfl(sv, j);
            float ww = __shfl(wv, j);
            unsigned hv = H2[(size_t)s * 64 + l];
            a0 = fmaf(ww, bflo(hv), a0);
            a1 = fmaf(ww, bfhi(hv), a1);
        }
    }
    unsigned xv = X02[(size_t)n * 64 + l];
    a0 = 0.9f * a0 + 0.1f * bflo(xv);
    a1 = 0.9f * a1 + 0.1f * bfhi(xv);
    float2 tv = make_float2(a0, a1);
    *(float2*)&T[(size_t)n * HID + l * 2] = tv;
}

// ---------------- layer gemm: H = relu((1-beta)*T + beta*(T@W)), bf16 MFMA ----------------
__global__ __launch_bounds__(256) void layer_gemm_mfma(const float* __restrict__ T,
                                                       const __hip_bfloat16* __restrict__ WTl,
                                                       float beta,
                                                       __hip_bfloat16* __restrict__ Hb,
                                                       float* __restrict__ Hf) {
    __shared__ short Tb[128 * 128];
    __shared__ short Wt[128 * 128];
    int tid = threadIdx.x;
    int w = tid >> 6, l = tid & 63, g = l >> 4, r = l & 15;
    int row0 = blockIdx.x * 128;
#pragma unroll
    for (int i = 0; i < 8; ++i) {
        int id = i * 256 + tid;
        int rr = id >> 4, slot = id & 15;
        int grow = row0 + rr;
        float4 v0 = make_float4(0.f, 0.f, 0.f, 0.f), v1 = v0;
        if (grow < NN) {
            v0 = *(const float4*)&T[(size_t)grow * HID + slot * 8];
            v1 = *(const float4*)&T[(size_t)grow * HID + slot * 8 + 4];
        }
        short8 p;
        p[0] = f2bf(v0.x); p[1] = f2bf(v0.y); p[2] = f2bf(v0.z); p[3] = f2bf(v0.w);
        p[4] = f2bf(v1.x); p[5] = f2bf(v1.y); p[6] = f2bf(v1.z); p[7] = f2bf(v1.w);
        *(short8*)&Tb[rr * 128 + (slot ^ (rr & 15)) * 8] = p;
        // W tile (pre-transposed bf16): n = id>>4, slot = id&15 -> offset id*8
        uint4 wv = *(const uint4*)&WTl[(size_t)id * 8];
        *(uint4*)&Wt[rr * 128 + (slot ^ (rr & 15)) * 8] = wv;
    }
    __syncthreads();
    f32x4 acc[2][8] = {};
#pragma unroll
    for (int ks = 0; ks < 4; ++ks) {
        short8 a[2], bb[8];
#pragma unroll
        for (int m = 0; m < 2; ++m) {
            int row = w * 32 + m * 16 + r;
            a[m] = *(short8*)&Tb[row * 128 + ((ks * 4 + g) ^ (row & 15)) * 8];
        }
#pragma unroll
        for (int n = 0; n < 8; ++n) {
            int col = n * 16 + r;
            bb[n] = *(short8*)&Wt[col * 128 + ((ks * 4 + g) ^ (col & 15)) * 8];
        }
#pragma unroll
        for (int m = 0; m < 2; ++m)
#pragma unroll
            for (int n = 0; n < 8; ++n)
                acc[m][n] = __builtin_amdgcn_mfma_f32_16x16x32_bf16(a[m], bb[n], acc[m][n], 0, 0, 0);
    }
    float omb = 1.0f - beta;
#pragma unroll
    for (int m = 0; m < 2; ++m) {
#pragma unroll
        for (int n = 0; n < 8; ++n) {
            int col = n * 16 + r;
#pragma unroll
            for (int q = 0; q < 4; ++q) {
                int row = row0 + w * 32 + m * 16 + g * 4 + q;
                if (row < NN) {
                    float tv = T[(size_t)row * HID + col];
                    float v = fmaxf(omb * tv + beta * acc[m][n][q], 0.f);
                    if (Hf) Hf[(size_t)row * HID + col] = v;
                    else    Hb[(size_t)row * HID + col] = __float2bfloat16(v);
                }
            }
        }
    }
}

// ---------------- final: log_softmax(z @ W_out + b_out); z already in d_out ----------------
__global__ __launch_bounds__(64) void final_kernel(const float* __restrict__ Z,
                                                   const float* __restrict__ Wout,
                                                   const float* __restrict__ bout,
                                                   float* __restrict__ lo) {
    int n = blockIdx.x;
    int c = threadIdx.x;  // 64 threads = 1 wave
    float logit = bout[c];
    for (int k = 0; k < HID; ++k) {
        logit = fmaf(Z[(size_t)n * HID + k], Wout[k * C_OUT + c], logit);
    }
    float m = logit;
#pragma unroll
    for (int off = 32; off; off >>= 1) m = fmaxf(m, __shfl_xor(m, off));
    float ex = __expf(logit - m);
    float ssum = ex;
#pragma unroll
    for (int off = 32; off; off >>= 1) ssum += __shfl_xor(ssum, off);
    lo[(size_t)n * C_OUT + c] = logit - m - logf(ssum);
}

extern "C" void kernel_launch(void* const* d_in, const int* in_sizes, int n_in,
                              void* d_out, int out_size, void* d_ws, size_t ws_size,
                              hipStream_t stream) {
    const float* x = (const float*)d_in[0];
    const int* ei = (const int*)d_in[1];
    const int* src = ei;
    const int* dst = ei + NE;
    const float* W_in = (const float*)d_in[2];
    const float* b_in = (const float*)d_in[3];
    const float* W_convs = (const float*)d_in[4];
    const float* W_out = (const float*)d_in[5];
    const float* b_out = (const float*)d_in[6];
    float* out = (float*)d_out;

    char* ws = (char*)d_ws;
    float* dinv = (float*)ws;              ws += (size_t)NN * 4;
    int* row_ptr = (int*)ws;               ws += (size_t)(NN + 4) * 4;
    int* fill = (int*)ws;                  ws += (size_t)NN * 4;
    int* csr_src = (int*)ws;               ws += (size_t)NE * 4;
    float* csr_w = (float*)ws;             ws += (size_t)NE * 4;
    __hip_bfloat16* WT = (__hip_bfloat16*)ws;   ws += (size_t)L_LAYERS * HID * HID * 2;
    __hip_bfloat16* WinT = (__hip_bfloat16*)ws; ws += (size_t)F_IN * HID * 2;
    __hip_bfloat16* x0b = (__hip_bfloat16*)ws;  ws += (size_t)NN * HID * 2;
    __hip_bfloat16* Hb = (__hip_bfloat16*)ws;   ws += (size_t)NN * HID * 2;
    float* T = (float*)ws;                 ws += (size_t)NN * HID * 4;

    hipMemsetAsync(fill, 0, (size_t)NN * 4, stream);
    count_deg<<<(NE + 255) / 256, 256, 0, stream>>>(dst, fill);
    compute_dinv<<<(NN + 255) / 256, 256, 0, stream>>>(fill, dinv);
    scan_rowptr<<<1, 256, 0, stream>>>(fill, row_ptr);
    hipMemcpyAsync(fill, row_ptr, (size_t)NN * 4, hipMemcpyDeviceToDevice, stream);
    scatter_csr<<<(NE + 255) / 256, 256, 0, stream>>>(src, dst, dinv, fill, csr_src, csr_w);
    prep_wt<<<80, 256, 0, stream>>>(W_convs, W_in, WT, WinT);

    int gemm_blocks = (NN + 127) / 128;
    gemm_x0_mfma<<<gemm_blocks, 256, 0, stream>>>(x, WinT, b_in, x0b);

    float* zf = out;  // last layer writes fp32 z directly into d_out
    for (int l = 0; l < L_LAYERS; ++l) {
        const __hip_bfloat16* h_in = (l == 0) ? x0b : Hb;
        float beta = logf(0.5f / (float)(l + 1) + 1.0f);
        spmm_bf16<<<NN / 4, 256, 0, stream>>>((const unsigned*)h_in, (const unsigned*)x0b,
                                              dinv, row_ptr, csr_src, csr_w, T);
        bool last = (l == L_LAYERS - 1);
        layer_gemm_mfma<<<gemm_blocks, 256, 0, stream>>>(
            T, WT + (size_t)l * HID * HID, beta,
            Hb, last ? zf : (float*)nullptr);
    }

    final_kernel<<<NN, 64, 0, stream>>>(zf, W_out, b_out, out + (size_t)NN * HID);
}

// Round 3
// 9407.204 us; speedup vs baseline: 1.5368x; 1.1533x over previous
//
#include <hip/hip_runtime.h>
#include <hip/hip_bf16.h>

#define NN 100000
#define NE 1600000
#define F_IN 512
#define HID 128
#define C_OUT 64
#define L_LAYERS 64
#define SCAN_NB 98  // ceil(NN/1024)

using short8 = __attribute__((ext_vector_type(8))) short;
using f32x4  = __attribute__((ext_vector_type(4))) float;

__device__ __forceinline__ short f2bf(float f) {
    __hip_bfloat16 h = __float2bfloat16(f);
    return __builtin_bit_cast(short, h);
}
__device__ __forceinline__ float bflo(unsigned u) { return __uint_as_float(u << 16); }
__device__ __forceinline__ float bfhi(unsigned u) { return __uint_as_float(u & 0xffff0000u); }

// ---------------- preprocessing ----------------

__global__ void count_deg(const int* __restrict__ dst, int* __restrict__ cnt) {
    int e = blockIdx.x * blockDim.x + threadIdx.x;
    if (e < NE) atomicAdd(&cnt[dst[e]], 1);
}

__global__ void compute_dinv(const int* __restrict__ cnt, float* __restrict__ dinv) {
    int n = blockIdx.x * blockDim.x + threadIdx.x;
    if (n < NN) dinv[n] = rsqrtf((float)cnt[n] + 1.0f);
}

// pass 1: per-block (1024 elems) local exclusive scan -> row_ptr, block sum -> partial
__global__ __launch_bounds__(256) void scan1(const int* __restrict__ cnt,
                                             int* __restrict__ row_ptr,
                                             int* __restrict__ partial) {
    __shared__ int sdata[256];
    int tid = threadIdx.x;
    int base = blockIdx.x * 1024;
    int v[4];
    int idx0 = base + tid * 4;
#pragma unroll
    for (int i = 0; i < 4; ++i) {
        int idx = idx0 + i;
        v[i] = (idx < NN) ? cnt[idx] : 0;
    }
    int s = v[0] + v[1] + v[2] + v[3];
    sdata[tid] = s;
    __syncthreads();
    int x = s;
    for (int off = 1; off < 256; off <<= 1) {
        int y = (tid >= off) ? sdata[tid - off] : 0;
        __syncthreads();
        x += y;
        sdata[tid] = x;
        __syncthreads();
    }
    int run = x - s;
#pragma unroll
    for (int i = 0; i < 4; ++i) {
        int idx = idx0 + i;
        if (idx < NN) row_ptr[idx] = run;
        run += v[i];
    }
    if (tid == 255) partial[blockIdx.x] = x;
}

// pass 2: exclusive scan of SCAN_NB partials (single small block)
__global__ __launch_bounds__(128) void scan2(int* __restrict__ partial) {
    __shared__ int sdata[128];
    int tid = threadIdx.x;
    int v = (tid < SCAN_NB) ? partial[tid] : 0;
    sdata[tid] = v;
    __syncthreads();
    int x = v;
    for (int off = 1; off < 128; off <<= 1) {
        int y = (tid >= off) ? sdata[tid - off] : 0;
        __syncthreads();
        x += y;
        sdata[tid] = x;
        __syncthreads();
    }
    if (tid < SCAN_NB) partial[tid] = x - v;  // exclusive
}

// pass 3: add block offsets
__global__ void scan3(int* __restrict__ row_ptr, const int* __restrict__ partial) {
    int idx = blockIdx.x * blockDim.x + threadIdx.x;
    if (idx < NN) row_ptr[idx] += partial[idx >> 10];
    if (idx == 0) row_ptr[NN] = NE;
}

__global__ void scatter_csr(const int* __restrict__ src, const int* __restrict__ dst,
                            const float* __restrict__ dinv, int* __restrict__ fill,
                            int* __restrict__ csr_src, float* __restrict__ csr_w) {
    int e = blockIdx.x * blockDim.x + threadIdx.x;
    if (e >= NE) return;
    int s = src[e], d = dst[e];
    int pos = atomicAdd(&fill[d], 1);
    csr_src[pos] = s;
    csr_w[pos] = dinv[s] * dinv[d];
}

// convert/transposed weights to bf16
__global__ __launch_bounds__(256) void prep_wt(const float* __restrict__ Wc,
                                               const float* __restrict__ Win,
                                               __hip_bfloat16* __restrict__ WT,
                                               __hip_bfloat16* __restrict__ WinT) {
    int b = blockIdx.x, tid = threadIdx.x;
    if (b < 64) {
        const float* src = Wc + (size_t)b * HID * HID;
        __hip_bfloat16* dstp = WT + (size_t)b * HID * HID;
        for (int it = 0; it < 64; ++it) {
            int idx = it * 256 + tid;           // n*128 + k
            int n = idx >> 7, k = idx & 127;
            dstp[idx] = __float2bfloat16(src[k * HID + n]);
        }
    } else {
        int j = b - 64;
        for (int it = 0; it < 16; ++it) {
            int gid = j * 4096 + it * 256 + tid;  // n*512 + k
            int n = gid >> 9, k = gid & 511;
            WinT[gid] = __float2bfloat16(Win[k * HID + n]);
        }
    }
}

// ---------------- x0 = relu(X @ W_in + b), bf16 MFMA, output bf16 ----------------
__global__ __launch_bounds__(256) void gemm_x0_mfma(const float* __restrict__ X,
                                                    const __hip_bfloat16* __restrict__ WinT,
                                                    const float* __restrict__ bias,
                                                    __hip_bfloat16* __restrict__ X0b) {
    __shared__ short Xs[128 * 32];
    __shared__ short Ws[128 * 32];
    int tid = threadIdx.x;
    int w = tid >> 6, l = tid & 63, g = l >> 4, r = l & 15;
    int row0 = blockIdx.x * 128;
    f32x4 acc[2][8] = {};

    for (int kt = 0; kt < 16; ++kt) {
        int k0 = kt * 32;
#pragma unroll
        for (int i = 0; i < 2; ++i) {
            int id = i * 256 + tid;
            int rr = id >> 2, slot = id & 3;
            int grow = row0 + rr;
            float4 v0 = make_float4(0.f, 0.f, 0.f, 0.f), v1 = v0;
            if (grow < NN) {
                v0 = *(const float4*)&X[(size_t)grow * F_IN + k0 + slot * 8];
                v1 = *(const float4*)&X[(size_t)grow * F_IN + k0 + slot * 8 + 4];
            }
            short8 p;
            p[0] = f2bf(v0.x); p[1] = f2bf(v0.y); p[2] = f2bf(v0.z); p[3] = f2bf(v0.w);
            p[4] = f2bf(v1.x); p[5] = f2bf(v1.y); p[6] = f2bf(v1.z); p[7] = f2bf(v1.w);
            *(short8*)&Xs[rr * 32 + slot * 8] = p;
        }
#pragma unroll
        for (int i = 0; i < 2; ++i) {
            int id = i * 256 + tid;
            int nn = id >> 2, slot = id & 3;
            uint4 wv = *(const uint4*)&WinT[(size_t)nn * F_IN + k0 + slot * 8];
            *(uint4*)&Ws[nn * 32 + slot * 8] = wv;
        }
        __syncthreads();
        short8 a[2], bb[8];
#pragma unroll
        for (int m = 0; m < 2; ++m)
            a[m] = *(short8*)&Xs[(w * 32 + m * 16 + r) * 32 + g * 8];
#pragma unroll
        for (int n = 0; n < 8; ++n)
            bb[n] = *(short8*)&Ws[(n * 16 + r) * 32 + g * 8];
#pragma unroll
        for (int m = 0; m < 2; ++m)
#pragma unroll
            for (int n = 0; n < 8; ++n)
                acc[m][n] = __builtin_amdgcn_mfma_f32_16x16x32_bf16(a[m], bb[n], acc[m][n], 0, 0, 0);
        __syncthreads();
    }
#pragma unroll
    for (int m = 0; m < 2; ++m) {
#pragma unroll
        for (int n = 0; n < 8; ++n) {
            int col = n * 16 + r;
            float bv = bias[col];
#pragma unroll
            for (int q = 0; q < 4; ++q) {
                int row = row0 + w * 32 + m * 16 + g * 4 + q;
                if (row < NN) {
                    float v = fmaxf(acc[m][n][q] + bv, 0.f);
                    X0b[(size_t)row * HID + col] = __float2bfloat16(v);
                }
            }
        }
    }
}

// ---------------- spmm + residual: T = 0.9*(A_hat h) + 0.1*x0, bf16 gather, fp32 out ----------------
// one wave per node; 8-deep unrolled edge loop for memory-level parallelism
__global__ __launch_bounds__(256) void spmm_bf16(const unsigned* __restrict__ H2,
                                                 const unsigned* __restrict__ X02,
                                                 const float* __restrict__ dinv,
                                                 const int* __restrict__ row_ptr,
                                                 const int* __restrict__ csr_src,
                                                 const float* __restrict__ csr_w,
                                                 float* __restrict__ T) {
    int n = blockIdx.x * 4 + (threadIdx.x >> 6);
    if (n >= NN) return;
    int l = threadIdx.x & 63;
    float dv = dinv[n];
    unsigned hs = H2[(size_t)n * 64 + l];
    float sw = dv * dv;
    float a0 = sw * bflo(hs), a1 = sw * bfhi(hs);
    int e0 = row_ptr[n], e1 = row_ptr[n + 1];
    for (int base = e0; base < e1; base += 64) {
        int cnt = e1 - base; if (cnt > 64) cnt = 64;
        int idx = base + l;
        int   sv = (idx < e1) ? csr_src[idx] : 0;
        float wv = (idx < e1) ? csr_w[idx] : 0.f;
        int j = 0;
        for (; j + 7 < cnt; j += 8) {
            unsigned hv[8];
            float ww[8];
#pragma unroll
            for (int u = 0; u < 8; ++u) {
                int s = __shfl(sv, j + u);
                ww[u] = __shfl(wv, j + u);
                hv[u] = H2[(size_t)s * 64 + l];
            }
#pragma unroll
            for (int u = 0; u < 8; ++u) {
                a0 = fmaf(ww[u], bflo(hv[u]), a0);
                a1 = fmaf(ww[u], bfhi(hv[u]), a1);
            }
        }
        for (; j < cnt; ++j) {
            int s = __shfl(sv, j);
            float ww = __shfl(wv, j);
            unsigned hv = H2[(size_t)s * 64 + l];
            a0 = fmaf(ww, bflo(hv), a0);
            a1 = fmaf(ww, bfhi(hv), a1);
        }
    }
    unsigned xv = X02[(size_t)n * 64 + l];
    a0 = 0.9f * a0 + 0.1f * bflo(xv);
    a1 = 0.9f * a1 + 0.1f * bfhi(xv);
    float2 tv = make_float2(a0, a1);
    *(float2*)&T[(size_t)n * HID + l * 2] = tv;
}

// ---------------- layer gemm: H = relu((1-beta)*T + beta*(T@W)), bf16 MFMA ----------------
__global__ __launch_bounds__(256) void layer_gemm_mfma(const float* __restrict__ T,
                                                       const __hip_bfloat16* __restrict__ WTl,
                                                       float beta,
                                                       __hip_bfloat16* __restrict__ Hb,
                                                       float* __restrict__ Hf) {
    __shared__ short Tb[128 * 128];
    __shared__ short Wt[128 * 128];
    int tid = threadIdx.x;
    int w = tid >> 6, l = tid & 63, g = l >> 4, r = l & 15;
    int row0 = blockIdx.x * 128;
#pragma unroll
    for (int i = 0; i < 8; ++i) {
        int id = i * 256 + tid;
        int rr = id >> 4, slot = id & 15;
        int grow = row0 + rr;
        float4 v0 = make_float4(0.f, 0.f, 0.f, 0.f), v1 = v0;
        if (grow < NN) {
            v0 = *(const float4*)&T[(size_t)grow * HID + slot * 8];
            v1 = *(const float4*)&T[(size_t)grow * HID + slot * 8 + 4];
        }
        short8 p;
        p[0] = f2bf(v0.x); p[1] = f2bf(v0.y); p[2] = f2bf(v0.z); p[3] = f2bf(v0.w);
        p[4] = f2bf(v1.x); p[5] = f2bf(v1.y); p[6] = f2bf(v1.z); p[7] = f2bf(v1.w);
        *(short8*)&Tb[rr * 128 + (slot ^ (rr & 15)) * 8] = p;
        uint4 wv = *(const uint4*)&WTl[(size_t)id * 8];
        *(uint4*)&Wt[rr * 128 + (slot ^ (rr & 15)) * 8] = wv;
    }
    __syncthreads();
    f32x4 acc[2][8] = {};
#pragma unroll
    for (int ks = 0; ks < 4; ++ks) {
        short8 a[2], bb[8];
#pragma unroll
        for (int m = 0; m < 2; ++m) {
            int row = w * 32 + m * 16 + r;
            a[m] = *(short8*)&Tb[row * 128 + ((ks * 4 + g) ^ (row & 15)) * 8];
        }
#pragma unroll
        for (int n = 0; n < 8; ++n) {
            int col = n * 16 + r;
            bb[n] = *(short8*)&Wt[col * 128 + ((ks * 4 + g) ^ (col & 15)) * 8];
        }
#pragma unroll
        for (int m = 0; m < 2; ++m)
#pragma unroll
            for (int n = 0; n < 8; ++n)
                acc[m][n] = __builtin_amdgcn_mfma_f32_16x16x32_bf16(a[m], bb[n], acc[m][n], 0, 0, 0);
    }
    float omb = 1.0f - beta;
#pragma unroll
    for (int m = 0; m < 2; ++m) {
#pragma unroll
        for (int n = 0; n < 8; ++n) {
            int col = n * 16 + r;
#pragma unroll
            for (int q = 0; q < 4; ++q) {
                int row = row0 + w * 32 + m * 16 + g * 4 + q;
                if (row < NN) {
                    float tv = T[(size_t)row * HID + col];
                    float v = fmaxf(omb * tv + beta * acc[m][n][q], 0.f);
                    if (Hf) Hf[(size_t)row * HID + col] = v;
                    else    Hb[(size_t)row * HID + col] = __float2bfloat16(v);
                }
            }
        }
    }
}

// ---------------- final: log_softmax(z @ W_out + b_out); z already in d_out ----------------
__global__ __launch_bounds__(64) void final_kernel(const float* __restrict__ Z,
                                                   const float* __restrict__ Wout,
                                                   const float* __restrict__ bout,
                                                   float* __restrict__ lo) {
    int n = blockIdx.x;
    int c = threadIdx.x;  // 64 threads = 1 wave
    float logit = bout[c];
    for (int k = 0; k < HID; ++k) {
        logit = fmaf(Z[(size_t)n * HID + k], Wout[k * C_OUT + c], logit);
    }
    float m = logit;
#pragma unroll
    for (int off = 32; off; off >>= 1) m = fmaxf(m, __shfl_xor(m, off));
    float ex = __expf(logit - m);
    float ssum = ex;
#pragma unroll
    for (int off = 32; off; off >>= 1) ssum += __shfl_xor(ssum, off);
    lo[(size_t)n * C_OUT + c] = logit - m - logf(ssum);
}

extern "C" void kernel_launch(void* const* d_in, const int* in_sizes, int n_in,
                              void* d_out, int out_size, void* d_ws, size_t ws_size,
                              hipStream_t stream) {
    const float* x = (const float*)d_in[0];
    const int* ei = (const int*)d_in[1];
    const int* src = ei;
    const int* dst = ei + NE;
    const float* W_in = (const float*)d_in[2];
    const float* b_in = (const float*)d_in[3];
    const float* W_convs = (const float*)d_in[4];
    const float* W_out = (const float*)d_in[5];
    const float* b_out = (const float*)d_in[6];
    float* out = (float*)d_out;

    char* ws = (char*)d_ws;
    float* dinv = (float*)ws;              ws += (size_t)NN * 4;
    int* row_ptr = (int*)ws;               ws += (size_t)(NN + 4) * 4;
    int* fill = (int*)ws;                  ws += (size_t)NN * 4;
    int* partial = (int*)ws;               ws += (size_t)128 * 4;
    int* csr_src = (int*)ws;               ws += (size_t)NE * 4;
    float* csr_w = (float*)ws;             ws += (size_t)NE * 4;
    __hip_bfloat16* WT = (__hip_bfloat16*)ws;   ws += (size_t)L_LAYERS * HID * HID * 2;
    __hip_bfloat16* WinT = (__hip_bfloat16*)ws; ws += (size_t)F_IN * HID * 2;
    __hip_bfloat16* x0b = (__hip_bfloat16*)ws;  ws += (size_t)NN * HID * 2;
    __hip_bfloat16* Hb = (__hip_bfloat16*)ws;   ws += (size_t)NN * HID * 2;
    float* T = (float*)ws;                 ws += (size_t)NN * HID * 4;

    hipMemsetAsync(fill, 0, (size_t)NN * 4, stream);
    count_deg<<<(NE + 255) / 256, 256, 0, stream>>>(dst, fill);
    compute_dinv<<<(NN + 255) / 256, 256, 0, stream>>>(fill, dinv);
    scan1<<<SCAN_NB, 256, 0, stream>>>(fill, row_ptr, partial);
    scan2<<<1, 128, 0, stream>>>(partial);
    scan3<<<(NN + 255) / 256, 256, 0, stream>>>(row_ptr, partial);
    hipMemcpyAsync(fill, row_ptr, (size_t)NN * 4, hipMemcpyDeviceToDevice, stream);
    scatter_csr<<<(NE + 255) / 256, 256, 0, stream>>>(src, dst, dinv, fill, csr_src, csr_w);
    prep_wt<<<80, 256, 0, stream>>>(W_convs, W_in, WT, WinT);

    int gemm_blocks = (NN + 127) / 128;
    gemm_x0_mfma<<<gemm_blocks, 256, 0, stream>>>(x, WinT, b_in, x0b);

    float* zf = out;  // last layer writes fp32 z directly into d_out
    for (int l = 0; l < L_LAYERS; ++l) {
        const __hip_bfloat16* h_in = (l == 0) ? x0b : Hb;
        float beta = logf(0.5f / (float)(l + 1) + 1.0f);
        spmm_bf16<<<NN / 4, 256, 0, stream>>>((const unsigned*)h_in, (const unsigned*)x0b,
                                              dinv, row_ptr, csr_src, csr_w, T);
        bool last = (l == L_LAYERS - 1);
        layer_gemm_mfma<<<gemm_blocks, 256, 0, stream>>>(
            T, WT + (size_t)l * HID * HID, beta,
            Hb, last ? zf : (float*)nullptr);
    }

    final_kernel<<<NN, 64, 0, stream>>>(zf, W_out, b_out, out + (size_t)NN * HID);
}

// Round 4
// 8504.453 us; speedup vs baseline: 1.7000x; 1.1062x over previous
//
#include <hip/hip_runtime.h>
#include <hip/hip_bf16.h>

#define NN 100000
#define NE 1600000
#define F_IN 512
#define HID 128
#define C_OUT 64
#define L_LAYERS 64
#define SCAN_NB 98  // ceil(NN/1024)

using short8 = __attribute__((ext_vector_type(8))) short;
using f32x4  = __attribute__((ext_vector_type(4))) float;
typedef __attribute__((ext_vector_type(4))) unsigned short ushort4v;

__device__ __forceinline__ short f2bf(float f) {
    __hip_bfloat16 h = __float2bfloat16(f);
    return __builtin_bit_cast(short, h);
}
__device__ __forceinline__ unsigned short f2bfu(float f) {
    __hip_bfloat16 h = __float2bfloat16(f);
    return __builtin_bit_cast(unsigned short, h);
}
__device__ __forceinline__ float bflo(unsigned u) { return __uint_as_float(u << 16); }
__device__ __forceinline__ float bfhi(unsigned u) { return __uint_as_float(u & 0xffff0000u); }
__device__ __forceinline__ float bf2f(unsigned short u) { return __uint_as_float((unsigned)u << 16); }

// ---------------- preprocessing ----------------

__global__ void count_deg(const int* __restrict__ dst, int* __restrict__ cnt) {
    int e = blockIdx.x * blockDim.x + threadIdx.x;
    if (e < NE) atomicAdd(&cnt[dst[e]], 1);
}

__global__ void compute_dinv(const int* __restrict__ cnt, float* __restrict__ dinv) {
    int n = blockIdx.x * blockDim.x + threadIdx.x;
    if (n < NN) dinv[n] = rsqrtf((float)cnt[n] + 1.0f);
}

__global__ __launch_bounds__(256) void scan1(const int* __restrict__ cnt,
                                             int* __restrict__ row_ptr,
                                             int* __restrict__ partial) {
    __shared__ int sdata[256];
    int tid = threadIdx.x;
    int base = blockIdx.x * 1024;
    int v[4];
    int idx0 = base + tid * 4;
#pragma unroll
    for (int i = 0; i < 4; ++i) {
        int idx = idx0 + i;
        v[i] = (idx < NN) ? cnt[idx] : 0;
    }
    int s = v[0] + v[1] + v[2] + v[3];
    sdata[tid] = s;
    __syncthreads();
    int x = s;
    for (int off = 1; off < 256; off <<= 1) {
        int y = (tid >= off) ? sdata[tid - off] : 0;
        __syncthreads();
        x += y;
        sdata[tid] = x;
        __syncthreads();
    }
    int run = x - s;
#pragma unroll
    for (int i = 0; i < 4; ++i) {
        int idx = idx0 + i;
        if (idx < NN) row_ptr[idx] = run;
        run += v[i];
    }
    if (tid == 255) partial[blockIdx.x] = x;
}

__global__ __launch_bounds__(128) void scan2(int* __restrict__ partial) {
    __shared__ int sdata[128];
    int tid = threadIdx.x;
    int v = (tid < SCAN_NB) ? partial[tid] : 0;
    sdata[tid] = v;
    __syncthreads();
    int x = v;
    for (int off = 1; off < 128; off <<= 1) {
        int y = (tid >= off) ? sdata[tid - off] : 0;
        __syncthreads();
        x += y;
        sdata[tid] = x;
        __syncthreads();
    }
    if (tid < SCAN_NB) partial[tid] = x - v;
}

__global__ void scan3(int* __restrict__ row_ptr, const int* __restrict__ partial) {
    int idx = blockIdx.x * blockDim.x + threadIdx.x;
    if (idx < NN) row_ptr[idx] += partial[idx >> 10];
    if (idx == 0) row_ptr[NN] = NE;
}

__global__ void scatter_csr(const int* __restrict__ src, const int* __restrict__ dst,
                            const float* __restrict__ dinv, int* __restrict__ fill,
                            int* __restrict__ csr_src, float* __restrict__ csr_w) {
    int e = blockIdx.x * blockDim.x + threadIdx.x;
    if (e >= NE) return;
    int s = src[e], d = dst[e];
    int pos = atomicAdd(&fill[d], 1);
    csr_src[pos] = s;
    csr_w[pos] = dinv[s] * dinv[d];
}

__global__ __launch_bounds__(256) void prep_wt(const float* __restrict__ Wc,
                                               const float* __restrict__ Win,
                                               __hip_bfloat16* __restrict__ WT,
                                               __hip_bfloat16* __restrict__ WinT) {
    int b = blockIdx.x, tid = threadIdx.x;
    if (b < 64) {
        const float* src = Wc + (size_t)b * HID * HID;
        __hip_bfloat16* dstp = WT + (size_t)b * HID * HID;
        for (int it = 0; it < 64; ++it) {
            int idx = it * 256 + tid;           // n*128 + k
            int n = idx >> 7, k = idx & 127;
            dstp[idx] = __float2bfloat16(src[k * HID + n]);
        }
    } else {
        int j = b - 64;
        for (int it = 0; it < 16; ++it) {
            int gid = j * 4096 + it * 256 + tid;  // n*512 + k
            int n = gid >> 9, k = gid & 511;
            WinT[gid] = __float2bfloat16(Win[k * HID + n]);
        }
    }
}

// ---------------- x0 = relu(X @ W_in + b), bf16 MFMA, software-pipelined ----------------
__global__ __launch_bounds__(256) void gemm_x0_mfma(const float* __restrict__ X,
                                                    const __hip_bfloat16* __restrict__ WinT,
                                                    const float* __restrict__ bias,
                                                    __hip_bfloat16* __restrict__ X0b) {
    __shared__ short Xs[128 * 32];
    __shared__ short Ws[128 * 32];
    int tid = threadIdx.x;
    int w = tid >> 6, l = tid & 63, g = l >> 4, r = l & 15;
    int row0 = blockIdx.x * 128;
    f32x4 acc[2][8] = {};

    float4 sx0[2], sx1[2];
    uint4 sw[2];
    auto load_tile = [&](int kt) {
        int k0 = kt * 32;
#pragma unroll
        for (int i = 0; i < 2; ++i) {
            int id = i * 256 + tid;
            int rr = id >> 2, slot = id & 3;
            int grow = row0 + rr;
            sx0[i] = make_float4(0.f, 0.f, 0.f, 0.f); sx1[i] = sx0[i];
            if (grow < NN) {
                sx0[i] = *(const float4*)&X[(size_t)grow * F_IN + k0 + slot * 8];
                sx1[i] = *(const float4*)&X[(size_t)grow * F_IN + k0 + slot * 8 + 4];
            }
            int idw = i * 256 + tid;
            int rw = idw >> 2, slw = idw & 3;
            sw[i] = *(const uint4*)&WinT[(size_t)rw * F_IN + k0 + slw * 8];
        }
    };

    load_tile(0);
    for (int kt = 0; kt < 16; ++kt) {
#pragma unroll
        for (int i = 0; i < 2; ++i) {
            int id = i * 256 + tid;
            int rr = id >> 2, slot = id & 3;
            short8 p;
            p[0] = f2bf(sx0[i].x); p[1] = f2bf(sx0[i].y); p[2] = f2bf(sx0[i].z); p[3] = f2bf(sx0[i].w);
            p[4] = f2bf(sx1[i].x); p[5] = f2bf(sx1[i].y); p[6] = f2bf(sx1[i].z); p[7] = f2bf(sx1[i].w);
            *(short8*)&Xs[rr * 32 + (slot ^ ((rr >> 1) & 3)) * 8] = p;
            *(uint4*)&Ws[rr * 32 + (slot ^ ((rr >> 1) & 3)) * 8] = sw[i];
        }
        __syncthreads();
        if (kt < 15) load_tile(kt + 1);
        short8 a[2], bb[8];
#pragma unroll
        for (int m = 0; m < 2; ++m) {
            int row = w * 32 + m * 16 + r;
            a[m] = *(short8*)&Xs[row * 32 + (g ^ ((row >> 1) & 3)) * 8];
        }
#pragma unroll
        for (int n = 0; n < 8; ++n) {
            int row = n * 16 + r;
            bb[n] = *(short8*)&Ws[row * 32 + (g ^ ((row >> 1) & 3)) * 8];
        }
#pragma unroll
        for (int m = 0; m < 2; ++m)
#pragma unroll
            for (int n = 0; n < 8; ++n)
                acc[m][n] = __builtin_amdgcn_mfma_f32_16x16x32_bf16(a[m], bb[n], acc[m][n], 0, 0, 0);
        __syncthreads();
    }
#pragma unroll
    for (int m = 0; m < 2; ++m) {
#pragma unroll
        for (int n = 0; n < 8; ++n) {
            int col = n * 16 + r;
            float bv = bias[col];
#pragma unroll
            for (int q = 0; q < 4; ++q) {
                int row = row0 + w * 32 + m * 16 + g * 4 + q;
                if (row < NN) {
                    float v = fmaxf(acc[m][n][q] + bv, 0.f);
                    X0b[(size_t)row * HID + col] = __float2bfloat16(v);
                }
            }
        }
    }
}

// ---------------- fused layer: gather(spmm)+residual -> LDS t (bf16) -> MFMA t@W -> relu store ----------------
// 512 threads = 8 waves; block tile = 128 nodes; LDS: Ts 32KB + Ws 32KB
__global__ __launch_bounds__(512, 4) void layer_fused(const unsigned* __restrict__ H2,
                                                      const unsigned* __restrict__ X02,
                                                      const float* __restrict__ dinv,
                                                      const int* __restrict__ row_ptr,
                                                      const int* __restrict__ csr_src,
                                                      const float* __restrict__ csr_w,
                                                      const __hip_bfloat16* __restrict__ WTl,
                                                      float beta,
                                                      __hip_bfloat16* __restrict__ Hout,
                                                      float* __restrict__ Zf) {
    __shared__ short Ts[128 * 128];
    __shared__ short Ws[128 * 128];
    int tid = threadIdx.x;
    int w = tid >> 6, l = tid & 63, g = l >> 4, r = l & 15;
    int row0 = blockIdx.x * 128;

    // load W tile (swizzled 16-slot XOR)
#pragma unroll
    for (int i = 0; i < 4; ++i) {
        int id = i * 512 + tid;
        int rr = id >> 4, slot = id & 15;
        uint4 wv = *(const uint4*)&WTl[(size_t)id * 8];
        *(uint4*)&Ws[rr * 128 + (slot ^ (rr & 15)) * 8] = wv;
    }

    // gather phase: wave w -> nodes row0 + w*16 .. +15 (sequential)
    unsigned* TsU = (unsigned*)Ts;
    for (int i = 0; i < 16; ++i) {
        int rr = w * 16 + i;
        int n = row0 + rr;
        unsigned pk = 0;
        if (n < NN) {
            float dv = dinv[n];
            unsigned hs = H2[(size_t)n * 64 + l];
            float swt = dv * dv;
            float a0 = swt * bflo(hs), a1 = swt * bfhi(hs);
            int e0 = row_ptr[n], e1 = row_ptr[n + 1];
            for (int base = e0; base < e1; base += 64) {
                int cnt = e1 - base; if (cnt > 64) cnt = 64;
                int idx = base + l;
                int   sv = (idx < e1) ? csr_src[idx] : 0;
                float wv = (idx < e1) ? csr_w[idx] : 0.f;
                int j = 0;
                for (; j + 7 < cnt; j += 8) {
                    unsigned hv[8];
                    float ww[8];
#pragma unroll
                    for (int u = 0; u < 8; ++u) {
                        int s = __shfl(sv, j + u);
                        ww[u] = __shfl(wv, j + u);
                        hv[u] = H2[(size_t)s * 64 + l];
                    }
#pragma unroll
                    for (int u = 0; u < 8; ++u) {
                        a0 = fmaf(ww[u], bflo(hv[u]), a0);
                        a1 = fmaf(ww[u], bfhi(hv[u]), a1);
                    }
                }
                for (; j < cnt; ++j) {
                    int s = __shfl(sv, j);
                    float ww = __shfl(wv, j);
                    unsigned hv = H2[(size_t)s * 64 + l];
                    a0 = fmaf(ww, bflo(hv), a0);
                    a1 = fmaf(ww, bfhi(hv), a1);
                }
            }
            unsigned xv = X02[(size_t)n * 64 + l];
            a0 = 0.9f * a0 + 0.1f * bflo(xv);
            a1 = 0.9f * a1 + 0.1f * bfhi(xv);
            pk = (unsigned)f2bfu(a0) | ((unsigned)f2bfu(a1) << 16);
        }
        // lane l covers shorts 2l,2l+1 of row rr; swizzled uint write
        TsU[rr * 64 + ((l >> 2) ^ (rr & 15)) * 4 + (l & 3)] = pk;
    }
    __syncthreads();

    // MFMA phase: swapped operands -> D[channel-side][node-side]
    f32x4 acc[8] = {};
#pragma unroll
    for (int ks = 0; ks < 4; ++ks) {
        int rrT = w * 16 + r;
        short8 bT = *(short8*)&Ts[rrT * 128 + ((ks * 4 + g) ^ (rrT & 15)) * 8];
        short8 aW[8];
#pragma unroll
        for (int c = 0; c < 8; ++c) {
            int rrW = c * 16 + r;
            aW[c] = *(short8*)&Ws[rrW * 128 + ((ks * 4 + g) ^ (rrW & 15)) * 8];
        }
#pragma unroll
        for (int c = 0; c < 8; ++c)
            acc[c] = __builtin_amdgcn_mfma_f32_16x16x32_bf16(aW[c], bT, acc[c], 0, 0, 0);
    }

    // epilogue: lane holds channels c0..c0+3 of node (w*16+r)
    float omb = 1.0f - beta;
    int node = w * 16 + r;
    int grow = row0 + node;
    if (grow < NN) {
#pragma unroll
        for (int c = 0; c < 8; ++c) {
            int c0 = c * 16 + g * 4;
            int slotE = c0 >> 3, posE = c0 & 7;
            ushort4v tv = *(ushort4v*)&Ts[node * 128 + (slotE ^ (node & 15)) * 8 + posE];
            float o[4];
#pragma unroll
            for (int q = 0; q < 4; ++q)
                o[q] = fmaxf(omb * bf2f(tv[q]) + beta * acc[c][q], 0.f);
            if (Zf) {
                *(float4*)&Zf[(size_t)grow * HID + c0] = make_float4(o[0], o[1], o[2], o[3]);
            } else {
                ushort4v hv;
#pragma unroll
                for (int q = 0; q < 4; ++q) hv[q] = f2bfu(o[q]);
                *(ushort4v*)&Hout[(size_t)grow * HID + c0] = hv;
            }
        }
    }
}

// ---------------- final: log_softmax(z @ W_out + b_out); z already in d_out ----------------
__global__ __launch_bounds__(64) void final_kernel(const float* __restrict__ Z,
                                                   const float* __restrict__ Wout,
                                                   const float* __restrict__ bout,
                                                   float* __restrict__ lo) {
    int n = blockIdx.x;
    int c = threadIdx.x;  // 64 threads = 1 wave
    float logit = bout[c];
    for (int k = 0; k < HID; ++k) {
        logit = fmaf(Z[(size_t)n * HID + k], Wout[k * C_OUT + c], logit);
    }
    float m = logit;
#pragma unroll
    for (int off = 32; off; off >>= 1) m = fmaxf(m, __shfl_xor(m, off));
    float ex = __expf(logit - m);
    float ssum = ex;
#pragma unroll
    for (int off = 32; off; off >>= 1) ssum += __shfl_xor(ssum, off);
    lo[(size_t)n * C_OUT + c] = logit - m - logf(ssum);
}

extern "C" void kernel_launch(void* const* d_in, const int* in_sizes, int n_in,
                              void* d_out, int out_size, void* d_ws, size_t ws_size,
                              hipStream_t stream) {
    const float* x = (const float*)d_in[0];
    const int* ei = (const int*)d_in[1];
    const int* src = ei;
    const int* dst = ei + NE;
    const float* W_in = (const float*)d_in[2];
    const float* b_in = (const float*)d_in[3];
    const float* W_convs = (const float*)d_in[4];
    const float* W_out = (const float*)d_in[5];
    const float* b_out = (const float*)d_in[6];
    float* out = (float*)d_out;

    char* ws = (char*)d_ws;
    float* dinv = (float*)ws;              ws += (size_t)NN * 4;
    int* row_ptr = (int*)ws;               ws += (size_t)(NN + 4) * 4;
    int* fill = (int*)ws;                  ws += (size_t)NN * 4;
    int* partial = (int*)ws;               ws += (size_t)128 * 4;
    int* csr_src = (int*)ws;               ws += (size_t)NE * 4;
    float* csr_w = (float*)ws;             ws += (size_t)NE * 4;
    __hip_bfloat16* WT = (__hip_bfloat16*)ws;   ws += (size_t)L_LAYERS * HID * HID * 2;
    __hip_bfloat16* WinT = (__hip_bfloat16*)ws; ws += (size_t)F_IN * HID * 2;
    __hip_bfloat16* x0b = (__hip_bfloat16*)ws;  ws += (size_t)NN * HID * 2;
    __hip_bfloat16* HbA = (__hip_bfloat16*)ws;  ws += (size_t)NN * HID * 2;
    __hip_bfloat16* HbB = (__hip_bfloat16*)ws;  ws += (size_t)NN * HID * 2;

    hipMemsetAsync(fill, 0, (size_t)NN * 4, stream);
    count_deg<<<(NE + 255) / 256, 256, 0, stream>>>(dst, fill);
    compute_dinv<<<(NN + 255) / 256, 256, 0, stream>>>(fill, dinv);
    scan1<<<SCAN_NB, 256, 0, stream>>>(fill, row_ptr, partial);
    scan2<<<1, 128, 0, stream>>>(partial);
    scan3<<<(NN + 255) / 256, 256, 0, stream>>>(row_ptr, partial);
    hipMemcpyAsync(fill, row_ptr, (size_t)NN * 4, hipMemcpyDeviceToDevice, stream);
    scatter_csr<<<(NE + 255) / 256, 256, 0, stream>>>(src, dst, dinv, fill, csr_src, csr_w);
    prep_wt<<<80, 256, 0, stream>>>(W_convs, W_in, WT, WinT);

    int gemm_blocks = (NN + 127) / 128;
    gemm_x0_mfma<<<gemm_blocks, 256, 0, stream>>>(x, WinT, b_in, x0b);

    float* zf = out;  // last layer writes fp32 z directly into d_out
    for (int l = 0; l < L_LAYERS; ++l) {
        const __hip_bfloat16* h_in = (l == 0) ? x0b : ((l & 1) ? HbA : HbB);
        __hip_bfloat16* h_out = (l & 1) ? HbB : HbA;
        float beta = logf(0.5f / (float)(l + 1) + 1.0f);
        bool last = (l == L_LAYERS - 1);
        layer_fused<<<gemm_blocks, 512, 0, stream>>>(
            (const unsigned*)h_in, (const unsigned*)x0b, dinv, row_ptr, csr_src, csr_w,
            WT + (size_t)l * HID * HID, beta,
            h_out, last ? zf : (float*)nullptr);
    }

    final_kernel<<<NN, 64, 0, stream>>>(zf, W_out, b_out, out + (size_t)NN * HID);
}

// Round 5
// 7829.625 us; speedup vs baseline: 1.8465x; 1.0862x over previous
//
#include <hip/hip_runtime.h>
#include <hip/hip_bf16.h>

#define NN 100000
#define NE 1600000
#define F_IN 512
#define HID 128
#define C_OUT 64
#define L_LAYERS 64
#define SCAN_NB 98  // ceil(NN/1024)

using short8 = __attribute__((ext_vector_type(8))) short;
using f32x4  = __attribute__((ext_vector_type(4))) float;
typedef __attribute__((ext_vector_type(4))) unsigned short ushort4v;

__device__ __forceinline__ short f2bf(float f) {
    __hip_bfloat16 h = __float2bfloat16(f);
    return __builtin_bit_cast(short, h);
}
__device__ __forceinline__ unsigned short f2bfu(float f) {
    __hip_bfloat16 h = __float2bfloat16(f);
    return __builtin_bit_cast(unsigned short, h);
}
__device__ __forceinline__ float bflo(unsigned u) { return __uint_as_float(u << 16); }
__device__ __forceinline__ float bfhi(unsigned u) { return __uint_as_float(u & 0xffff0000u); }
__device__ __forceinline__ float bf2f(unsigned short u) { return __uint_as_float((unsigned)u << 16); }

// ---------------- preprocessing ----------------

__global__ void count_deg(const int* __restrict__ dst, int* __restrict__ cnt) {
    int e = blockIdx.x * blockDim.x + threadIdx.x;
    if (e < NE) atomicAdd(&cnt[dst[e]], 1);
}

__global__ void compute_dinv(const int* __restrict__ cnt, float* __restrict__ dinv) {
    int n = blockIdx.x * blockDim.x + threadIdx.x;
    if (n < NN) dinv[n] = rsqrtf((float)cnt[n] + 1.0f);
}

__global__ __launch_bounds__(256) void scan1(const int* __restrict__ cnt,
                                             int* __restrict__ row_ptr,
                                             int* __restrict__ partial) {
    __shared__ int sdata[256];
    int tid = threadIdx.x;
    int base = blockIdx.x * 1024;
    int v[4];
    int idx0 = base + tid * 4;
#pragma unroll
    for (int i = 0; i < 4; ++i) {
        int idx = idx0 + i;
        v[i] = (idx < NN) ? cnt[idx] : 0;
    }
    int s = v[0] + v[1] + v[2] + v[3];
    sdata[tid] = s;
    __syncthreads();
    int x = s;
    for (int off = 1; off < 256; off <<= 1) {
        int y = (tid >= off) ? sdata[tid - off] : 0;
        __syncthreads();
        x += y;
        sdata[tid] = x;
        __syncthreads();
    }
    int run = x - s;
#pragma unroll
    for (int i = 0; i < 4; ++i) {
        int idx = idx0 + i;
        if (idx < NN) row_ptr[idx] = run;
        run += v[i];
    }
    if (tid == 255) partial[blockIdx.x] = x;
}

__global__ __launch_bounds__(128) void scan2(int* __restrict__ partial) {
    __shared__ int sdata[128];
    int tid = threadIdx.x;
    int v = (tid < SCAN_NB) ? partial[tid] : 0;
    sdata[tid] = v;
    __syncthreads();
    int x = v;
    for (int off = 1; off < 128; off <<= 1) {
        int y = (tid >= off) ? sdata[tid - off] : 0;
        __syncthreads();
        x += y;
        sdata[tid] = x;
        __syncthreads();
    }
    if (tid < SCAN_NB) partial[tid] = x - v;
}

__global__ void scan3(int* __restrict__ row_ptr, const int* __restrict__ partial) {
    int idx = blockIdx.x * blockDim.x + threadIdx.x;
    if (idx < NN) row_ptr[idx] += partial[idx >> 10];
    if (idx == 0) row_ptr[NN] = NE;
}

// pack (src, weight-bits) per edge for scalar-load broadcast in the gather
__global__ void scatter_csr(const int* __restrict__ src, const int* __restrict__ dst,
                            const float* __restrict__ dinv, int* __restrict__ fill,
                            int2* __restrict__ edges) {
    int e = blockIdx.x * blockDim.x + threadIdx.x;
    if (e >= NE) return;
    int s = src[e], d = dst[e];
    int pos = atomicAdd(&fill[d], 1);
    edges[pos] = make_int2(s, __float_as_int(dinv[s] * dinv[d]));
}

__global__ __launch_bounds__(256) void prep_wt(const float* __restrict__ Wc,
                                               const float* __restrict__ Win,
                                               __hip_bfloat16* __restrict__ WT,
                                               __hip_bfloat16* __restrict__ WinT) {
    int b = blockIdx.x, tid = threadIdx.x;
    if (b < 64) {
        const float* src = Wc + (size_t)b * HID * HID;
        __hip_bfloat16* dstp = WT + (size_t)b * HID * HID;
        for (int it = 0; it < 64; ++it) {
            int idx = it * 256 + tid;           // n*128 + k
            int n = idx >> 7, k = idx & 127;
            dstp[idx] = __float2bfloat16(src[k * HID + n]);
        }
    } else {
        int j = b - 64;
        for (int it = 0; it < 16; ++it) {
            int gid = j * 4096 + it * 256 + tid;  // n*512 + k
            int n = gid >> 9, k = gid & 511;
            WinT[gid] = __float2bfloat16(Win[k * HID + n]);
        }
    }
}

// ---------------- x0 = relu(X @ W_in + b), bf16 MFMA, software-pipelined ----------------
__global__ __launch_bounds__(256) void gemm_x0_mfma(const float* __restrict__ X,
                                                    const __hip_bfloat16* __restrict__ WinT,
                                                    const float* __restrict__ bias,
                                                    __hip_bfloat16* __restrict__ X0b) {
    __shared__ short Xs[128 * 32];
    __shared__ short Ws[128 * 32];
    int tid = threadIdx.x;
    int w = tid >> 6, l = tid & 63, g = l >> 4, r = l & 15;
    int row0 = blockIdx.x * 128;
    f32x4 acc[2][8] = {};

    float4 sx0[2], sx1[2];
    uint4 sw[2];
    auto load_tile = [&](int kt) {
        int k0 = kt * 32;
#pragma unroll
        for (int i = 0; i < 2; ++i) {
            int id = i * 256 + tid;
            int rr = id >> 2, slot = id & 3;
            int grow = row0 + rr;
            sx0[i] = make_float4(0.f, 0.f, 0.f, 0.f); sx1[i] = sx0[i];
            if (grow < NN) {
                sx0[i] = *(const float4*)&X[(size_t)grow * F_IN + k0 + slot * 8];
                sx1[i] = *(const float4*)&X[(size_t)grow * F_IN + k0 + slot * 8 + 4];
            }
            sw[i] = *(const uint4*)&WinT[(size_t)rr * F_IN + k0 + slot * 8];
        }
    };

    load_tile(0);
    for (int kt = 0; kt < 16; ++kt) {
#pragma unroll
        for (int i = 0; i < 2; ++i) {
            int id = i * 256 + tid;
            int rr = id >> 2, slot = id & 3;
            short8 p;
            p[0] = f2bf(sx0[i].x); p[1] = f2bf(sx0[i].y); p[2] = f2bf(sx0[i].z); p[3] = f2bf(sx0[i].w);
            p[4] = f2bf(sx1[i].x); p[5] = f2bf(sx1[i].y); p[6] = f2bf(sx1[i].z); p[7] = f2bf(sx1[i].w);
            *(short8*)&Xs[rr * 32 + (slot ^ ((rr >> 1) & 3)) * 8] = p;
            *(uint4*)&Ws[rr * 32 + (slot ^ ((rr >> 1) & 3)) * 8] = sw[i];
        }
        __syncthreads();
        if (kt < 15) load_tile(kt + 1);
        short8 a[2], bb[8];
#pragma unroll
        for (int m = 0; m < 2; ++m) {
            int row = w * 32 + m * 16 + r;
            a[m] = *(short8*)&Xs[row * 32 + (g ^ ((row >> 1) & 3)) * 8];
        }
#pragma unroll
        for (int n = 0; n < 8; ++n) {
            int row = n * 16 + r;
            bb[n] = *(short8*)&Ws[row * 32 + (g ^ ((row >> 1) & 3)) * 8];
        }
#pragma unroll
        for (int m = 0; m < 2; ++m)
#pragma unroll
            for (int n = 0; n < 8; ++n)
                acc[m][n] = __builtin_amdgcn_mfma_f32_16x16x32_bf16(a[m], bb[n], acc[m][n], 0, 0, 0);
        __syncthreads();
    }
#pragma unroll
    for (int m = 0; m < 2; ++m) {
#pragma unroll
        for (int n = 0; n < 8; ++n) {
            int col = n * 16 + r;
            float bv = bias[col];
#pragma unroll
            for (int q = 0; q < 4; ++q) {
                int row = row0 + w * 32 + m * 16 + g * 4 + q;
                if (row < NN) {
                    float v = fmaxf(acc[m][n][q] + bv, 0.f);
                    X0b[(size_t)row * HID + col] = __float2bfloat16(v);
                }
            }
        }
    }
}

// ---------------- fused layer v2: 64-node tile, scalar edge loads, 8 waves ----------------
// 512 threads = 8 waves; each wave gathers 8 nodes; LDS: Ts 16KB + Ws 32KB = 48KB -> 3 blocks/CU
__global__ __launch_bounds__(512, 6) void layer_fused(const unsigned* __restrict__ H2,
                                                      const unsigned* __restrict__ X02,
                                                      const float* __restrict__ dinv,
                                                      const int* __restrict__ row_ptr,
                                                      const int2* __restrict__ edges,
                                                      const __hip_bfloat16* __restrict__ WTl,
                                                      float beta,
                                                      __hip_bfloat16* __restrict__ Hout,
                                                      float* __restrict__ Zf) {
    __shared__ short Ts[64 * 128];
    __shared__ short Ws[128 * 128];
    int tid = threadIdx.x;
    int w = tid >> 6, l = tid & 63, g = l >> 4, r = l & 15;
    int row0 = blockIdx.x * 64;

    // load W tile (swizzled 16-slot XOR): 2048 uint4 over 512 threads
#pragma unroll
    for (int i = 0; i < 4; ++i) {
        int id = i * 512 + tid;
        int rr = id >> 4, slot = id & 15;
        uint4 wv = *(const uint4*)&WTl[(size_t)id * 8];
        *(uint4*)&Ws[rr * 128 + (slot ^ (rr & 15)) * 8] = wv;
    }

    // gather phase: wave w -> nodes row0 + w*8 .. +7
    unsigned* TsU = (unsigned*)Ts;
    for (int i = 0; i < 8; ++i) {
        int rr = w * 8 + i;
        int n = row0 + rr;
        unsigned pk = 0;
        if (n < NN) {
            float dv = dinv[n];
            unsigned hs = H2[((unsigned)n << 6) + l];
            float swt = dv * dv;
            float a0 = swt * bflo(hs), a1 = swt * bfhi(hs);
            // wave-uniform edge range -> scalar loads for metadata
            int e0 = __builtin_amdgcn_readfirstlane(row_ptr[n]);
            int e1 = __builtin_amdgcn_readfirstlane(row_ptr[n + 1]);
            int e = e0;
            for (; e + 8 <= e1; e += 8) {
                int2 p[8];
#pragma unroll
                for (int u = 0; u < 8; ++u) p[u] = edges[e + u];
                unsigned hv[8];
#pragma unroll
                for (int u = 0; u < 8; ++u)
                    hv[u] = H2[((unsigned)p[u].x << 6) + l];
#pragma unroll
                for (int u = 0; u < 8; ++u) {
                    float ww = __int_as_float(p[u].y);
                    a0 = fmaf(ww, bflo(hv[u]), a0);
                    a1 = fmaf(ww, bfhi(hv[u]), a1);
                }
            }
            for (; e < e1; ++e) {
                int2 p = edges[e];
                unsigned hv = H2[((unsigned)p.x << 6) + l];
                float ww = __int_as_float(p.y);
                a0 = fmaf(ww, bflo(hv), a0);
                a1 = fmaf(ww, bfhi(hv), a1);
            }
            unsigned xv = X02[((unsigned)n << 6) + l];
            a0 = 0.9f * a0 + 0.1f * bflo(xv);
            a1 = 0.9f * a1 + 0.1f * bfhi(xv);
            pk = (unsigned)f2bfu(a0) | ((unsigned)f2bfu(a1) << 16);
        }
        TsU[rr * 64 + ((l >> 2) ^ (rr & 15)) * 4 + (l & 3)] = pk;
    }
    __syncthreads();

    // MFMA phase: wave w -> node-block nb = w&3 (16 nodes), channel-group cg = w>>2 (64 ch)
    int nb = w & 3, cg = w >> 2;
    f32x4 acc[4] = {};
#pragma unroll
    for (int ks = 0; ks < 4; ++ks) {
        int rrT = nb * 16 + r;
        short8 bT = *(short8*)&Ts[rrT * 128 + ((ks * 4 + g) ^ (rrT & 15)) * 8];
        short8 aW[4];
#pragma unroll
        for (int c = 0; c < 4; ++c) {
            int rrW = (cg * 4 + c) * 16 + r;
            aW[c] = *(short8*)&Ws[rrW * 128 + ((ks * 4 + g) ^ (rrW & 15)) * 8];
        }
#pragma unroll
        for (int c = 0; c < 4; ++c)
            acc[c] = __builtin_amdgcn_mfma_f32_16x16x32_bf16(aW[c], bT, acc[c], 0, 0, 0);
    }

    // epilogue: lane holds channels (cg*4+c)*16 + g*4 .. +3 of node nb*16+r
    float omb = 1.0f - beta;
    int node = nb * 16 + r;
    int grow = row0 + node;
    if (grow < NN) {
#pragma unroll
        for (int c = 0; c < 4; ++c) {
            int c0 = (cg * 4 + c) * 16 + g * 4;
            int slotE = c0 >> 3, posE = c0 & 7;
            ushort4v tv = *(ushort4v*)&Ts[node * 128 + (slotE ^ (node & 15)) * 8 + posE];
            float o[4];
#pragma unroll
            for (int q = 0; q < 4; ++q)
                o[q] = fmaxf(omb * bf2f(tv[q]) + beta * acc[c][q], 0.f);
            if (Zf) {
                *(float4*)&Zf[(size_t)grow * HID + c0] = make_float4(o[0], o[1], o[2], o[3]);
            } else {
                ushort4v hv;
#pragma unroll
                for (int q = 0; q < 4; ++q) hv[q] = f2bfu(o[q]);
                *(ushort4v*)&Hout[(size_t)grow * HID + c0] = hv;
            }
        }
    }
}

// ---------------- final: log_softmax(z @ W_out + b_out); z already in d_out ----------------
__global__ __launch_bounds__(64) void final_kernel(const float* __restrict__ Z,
                                                   const float* __restrict__ Wout,
                                                   const float* __restrict__ bout,
                                                   float* __restrict__ lo) {
    int n = blockIdx.x;
    int c = threadIdx.x;
    float logit = bout[c];
    for (int k = 0; k < HID; ++k) {
        logit = fmaf(Z[(size_t)n * HID + k], Wout[k * C_OUT + c], logit);
    }
    float m = logit;
#pragma unroll
    for (int off = 32; off; off >>= 1) m = fmaxf(m, __shfl_xor(m, off));
    float ex = __expf(logit - m);
    float ssum = ex;
#pragma unroll
    for (int off = 32; off; off >>= 1) ssum += __shfl_xor(ssum, off);
    lo[(size_t)n * C_OUT + c] = logit - m - logf(ssum);
}

extern "C" void kernel_launch(void* const* d_in, const int* in_sizes, int n_in,
                              void* d_out, int out_size, void* d_ws, size_t ws_size,
                              hipStream_t stream) {
    const float* x = (const float*)d_in[0];
    const int* ei = (const int*)d_in[1];
    const int* src = ei;
    const int* dst = ei + NE;
    const float* W_in = (const float*)d_in[2];
    const float* b_in = (const float*)d_in[3];
    const float* W_convs = (const float*)d_in[4];
    const float* W_out = (const float*)d_in[5];
    const float* b_out = (const float*)d_in[6];
    float* out = (float*)d_out;

    char* ws = (char*)d_ws;
    float* dinv = (float*)ws;              ws += (size_t)NN * 4;
    int* row_ptr = (int*)ws;               ws += (size_t)(NN + 4) * 4;
    int* fill = (int*)ws;                  ws += (size_t)NN * 4;
    int* partial = (int*)ws;               ws += (size_t)128 * 4;
    int2* edges = (int2*)ws;               ws += (size_t)NE * 8;
    __hip_bfloat16* WT = (__hip_bfloat16*)ws;   ws += (size_t)L_LAYERS * HID * HID * 2;
    __hip_bfloat16* WinT = (__hip_bfloat16*)ws; ws += (size_t)F_IN * HID * 2;
    __hip_bfloat16* x0b = (__hip_bfloat16*)ws;  ws += (size_t)NN * HID * 2;
    __hip_bfloat16* HbA = (__hip_bfloat16*)ws;  ws += (size_t)NN * HID * 2;
    __hip_bfloat16* HbB = (__hip_bfloat16*)ws;  ws += (size_t)NN * HID * 2;

    hipMemsetAsync(fill, 0, (size_t)NN * 4, stream);
    count_deg<<<(NE + 255) / 256, 256, 0, stream>>>(dst, fill);
    compute_dinv<<<(NN + 255) / 256, 256, 0, stream>>>(fill, dinv);
    scan1<<<SCAN_NB, 256, 0, stream>>>(fill, row_ptr, partial);
    scan2<<<1, 128, 0, stream>>>(partial);
    scan3<<<(NN + 255) / 256, 256, 0, stream>>>(row_ptr, partial);
    hipMemcpyAsync(fill, row_ptr, (size_t)NN * 4, hipMemcpyDeviceToDevice, stream);
    scatter_csr<<<(NE + 255) / 256, 256, 0, stream>>>(src, dst, dinv, fill, edges);
    prep_wt<<<80, 256, 0, stream>>>(W_convs, W_in, WT, WinT);

    int gemm_blocks = (NN + 127) / 128;
    gemm_x0_mfma<<<gemm_blocks, 256, 0, stream>>>(x, WinT, b_in, x0b);

    int layer_blocks = (NN + 63) / 64;
    float* zf = out;  // last layer writes fp32 z directly into d_out
    for (int l = 0; l < L_LAYERS; ++l) {
        const __hip_bfloat16* h_in = (l == 0) ? x0b : ((l & 1) ? HbA : HbB);
        __hip_bfloat16* h_out = (l & 1) ? HbB : HbA;
        float beta = logf(0.5f / (float)(l + 1) + 1.0f);
        bool last = (l == L_LAYERS - 1);
        layer_fused<<<layer_blocks, 512, 0, stream>>>(
            (const unsigned*)h_in, (const unsigned*)x0b, dinv, row_ptr, edges,
            WT + (size_t)l * HID * HID, beta,
            h_out, last ? zf : (float*)nullptr);
    }

    final_kernel<<<NN, 64, 0, stream>>>(zf, W_out, b_out, out + (size_t)NN * HID);
}

// Round 7
// 6368.799 us; speedup vs baseline: 2.2700x; 1.2294x over previous
//
#include <hip/hip_runtime.h>
#include <hip/hip_bf16.h>

#define NN 100000
#define NE 1600000
#define F_IN 512
#define HID 128
#define C_OUT 64
#define L_LAYERS 64
#define SCAN_NB 98  // ceil(NN/1024)

using short8 = __attribute__((ext_vector_type(8))) short;
using f32x4  = __attribute__((ext_vector_type(4))) float;
typedef __attribute__((ext_vector_type(4))) unsigned short ushort4v;

__device__ __forceinline__ short f2bf(float f) {
    __hip_bfloat16 h = __float2bfloat16(f);
    return __builtin_bit_cast(short, h);
}
__device__ __forceinline__ unsigned short f2bfu(float f) {
    __hip_bfloat16 h = __float2bfloat16(f);
    return __builtin_bit_cast(unsigned short, h);
}
__device__ __forceinline__ float bflo(unsigned u) { return __uint_as_float(u << 16); }
__device__ __forceinline__ float bfhi(unsigned u) { return __uint_as_float(u & 0xffff0000u); }
__device__ __forceinline__ float bf2f(unsigned short u) { return __uint_as_float((unsigned)u << 16); }

// ---------------- preprocessing ----------------

__global__ void count_deg(const int* __restrict__ dst, int* __restrict__ cnt) {
    int e = blockIdx.x * blockDim.x + threadIdx.x;
    if (e < NE) atomicAdd(&cnt[dst[e]], 1);
}

__global__ void compute_dinv(const int* __restrict__ cnt, float* __restrict__ dinv) {
    int n = blockIdx.x * blockDim.x + threadIdx.x;
    if (n < NN) dinv[n] = rsqrtf((float)cnt[n] + 1.0f);
}

__global__ __launch_bounds__(256) void scan1(const int* __restrict__ cnt,
                                             int* __restrict__ row_ptr,
                                             int* __restrict__ partial) {
    __shared__ int sdata[256];
    int tid = threadIdx.x;
    int base = blockIdx.x * 1024;
    int v[4];
    int idx0 = base + tid * 4;
#pragma unroll
    for (int i = 0; i < 4; ++i) {
        int idx = idx0 + i;
        v[i] = (idx < NN) ? cnt[idx] : 0;
    }
    int s = v[0] + v[1] + v[2] + v[3];
    sdata[tid] = s;
    __syncthreads();
    int x = s;
    for (int off = 1; off < 256; off <<= 1) {
        int y = (tid >= off) ? sdata[tid - off] : 0;
        __syncthreads();
        x += y;
        sdata[tid] = x;
        __syncthreads();
    }
    int run = x - s;
#pragma unroll
    for (int i = 0; i < 4; ++i) {
        int idx = idx0 + i;
        if (idx < NN) row_ptr[idx] = run;
        run += v[i];
    }
    if (tid == 255) partial[blockIdx.x] = x;
}

__global__ __launch_bounds__(128) void scan2(int* __restrict__ partial) {
    __shared__ int sdata[128];
    int tid = threadIdx.x;
    int v = (tid < SCAN_NB) ? partial[tid] : 0;
    sdata[tid] = v;
    __syncthreads();
    int x = v;
    for (int off = 1; off < 128; off <<= 1) {
        int y = (tid >= off) ? sdata[tid - off] : 0;
        __syncthreads();
        x += y;
        sdata[tid] = x;
        __syncthreads();
    }
    if (tid < SCAN_NB) partial[tid] = x - v;
}

// add block offsets; pad row_ptr[NN..NN+64] = NE for OOB wave preloads
__global__ void scan3(int* __restrict__ row_ptr, const int* __restrict__ partial) {
    int idx = blockIdx.x * blockDim.x + threadIdx.x;
    if (idx < NN) row_ptr[idx] += partial[idx >> 10];
    else if (idx <= NN + 64) row_ptr[idx] = NE;
}

// pack (src, weight-bits) per edge for scalar-load broadcast in the gather
__global__ void scatter_csr(const int* __restrict__ src, const int* __restrict__ dst,
                            const float* __restrict__ dinv, int* __restrict__ fill,
                            int2* __restrict__ edges) {
    int e = blockIdx.x * blockDim.x + threadIdx.x;
    if (e >= NE) return;
    int s = src[e], d = dst[e];
    int pos = atomicAdd(&fill[d], 1);
    edges[pos] = make_int2(s, __float_as_int(dinv[s] * dinv[d]));
}

__global__ __launch_bounds__(256) void prep_wt(const float* __restrict__ Wc,
                                               const float* __restrict__ Win,
                                               __hip_bfloat16* __restrict__ WT,
                                               __hip_bfloat16* __restrict__ WinT) {
    int b = blockIdx.x, tid = threadIdx.x;
    if (b < 64) {
        const float* src = Wc + (size_t)b * HID * HID;
        __hip_bfloat16* dstp = WT + (size_t)b * HID * HID;
        for (int it = 0; it < 64; ++it) {
            int idx = it * 256 + tid;           // n*128 + k
            int n = idx >> 7, k = idx & 127;
            dstp[idx] = __float2bfloat16(src[k * HID + n]);
        }
    } else {
        int j = b - 64;
        for (int it = 0; it < 16; ++it) {
            int gid = j * 4096 + it * 256 + tid;  // n*512 + k
            int n = gid >> 9, k = gid & 511;
            WinT[gid] = __float2bfloat16(Win[k * HID + n]);
        }
    }
}

// ---------------- x0 = relu(X @ W_in + b), bf16 MFMA, double-buffered, LDS-staged epilogue ----------------
__global__ __launch_bounds__(256) void gemm_x0_mfma(const float* __restrict__ X,
                                                    const __hip_bfloat16* __restrict__ WinT,
                                                    const float* __restrict__ bias,
                                                    __hip_bfloat16* __restrict__ X0b) {
    __shared__ short SMEM[128 * 128];  // 32KB: dbuf X/W tiles (4x 4096), then epilogue staging
    int tid = threadIdx.x;
    int w = tid >> 6, l = tid & 63, g = l >> 4, r = l & 15;
    int row0 = blockIdx.x * 128;
    f32x4 acc[2][8] = {};

    float4 sx0[2], sx1[2];
    uint4 sw[2];
    auto load_regs = [&](int kt) {
        int k0 = kt * 32;
#pragma unroll
        for (int i = 0; i < 2; ++i) {
            int id = i * 256 + tid;
            int rr = id >> 2, slot = id & 3;
            int grow = row0 + rr;
            sx0[i] = make_float4(0.f, 0.f, 0.f, 0.f); sx1[i] = sx0[i];
            if (grow < NN) {
                sx0[i] = *(const float4*)&X[(size_t)grow * F_IN + k0 + slot * 8];
                sx1[i] = *(const float4*)&X[(size_t)grow * F_IN + k0 + slot * 8 + 4];
            }
            sw[i] = *(const uint4*)&WinT[(size_t)rr * F_IN + k0 + slot * 8];
        }
    };

    load_regs(0);
    for (int kt = 0; kt < 16; ++kt) {
        short* Xs = SMEM + (kt & 1) * 4096;
        short* Wsh = SMEM + 8192 + (kt & 1) * 4096;
#pragma unroll
        for (int i = 0; i < 2; ++i) {
            int id = i * 256 + tid;
            int rr = id >> 2, slot = id & 3;
            short8 p;
            p[0] = f2bf(sx0[i].x); p[1] = f2bf(sx0[i].y); p[2] = f2bf(sx0[i].z); p[3] = f2bf(sx0[i].w);
            p[4] = f2bf(sx1[i].x); p[5] = f2bf(sx1[i].y); p[6] = f2bf(sx1[i].z); p[7] = f2bf(sx1[i].w);
            *(short8*)&Xs[rr * 32 + (slot ^ ((rr >> 1) & 3)) * 8] = p;
            *(uint4*)&Wsh[rr * 32 + (slot ^ ((rr >> 1) & 3)) * 8] = sw[i];
        }
        __syncthreads();
        if (kt < 15) load_regs(kt + 1);
        short8 a[2], bb[8];
#pragma unroll
        for (int m = 0; m < 2; ++m) {
            int row = w * 32 + m * 16 + r;
            a[m] = *(short8*)&Xs[row * 32 + (g ^ ((row >> 1) & 3)) * 8];
        }
#pragma unroll
        for (int n = 0; n < 8; ++n) {
            int row = n * 16 + r;
            bb[n] = *(short8*)&Wsh[row * 32 + (g ^ ((row >> 1) & 3)) * 8];
        }
#pragma unroll
        for (int m = 0; m < 2; ++m)
#pragma unroll
            for (int n = 0; n < 8; ++n)
                acc[m][n] = __builtin_amdgcn_mfma_f32_16x16x32_bf16(a[m], bb[n], acc[m][n], 0, 0, 0);
        // no second barrier: double-buffered; barrier sits between write and read of same buffer
    }
    __syncthreads();
    // stage bias+relu result into SMEM (swizzled 16B chunks), then coop vector store
#pragma unroll
    for (int m = 0; m < 2; ++m) {
#pragma unroll
        for (int n = 0; n < 8; ++n) {
            int col = n * 16 + r;
            float bv = bias[col];
#pragma unroll
            for (int q = 0; q < 4; ++q) {
                int row = w * 32 + m * 16 + g * 4 + q;
                float v = fmaxf(acc[m][n][q] + bv, 0.f);
                SMEM[row * 128 + ((col >> 3) ^ (row & 15)) * 8 + (col & 7)] = f2bf(v);
            }
        }
    }
    __syncthreads();
    // 128 rows x 16 chunks of 8 shorts = 2048 uint4 over 256 threads x 8 iters
#pragma unroll
    for (int i = 0; i < 8; ++i) {
        int id = i * 256 + tid;
        int rr = id >> 4, c8 = id & 15;
        int grow = row0 + rr;
        if (grow < NN)
            *(uint4*)&X0b[(size_t)grow * HID + c8 * 8] =
                *(uint4*)&SMEM[rr * 128 + ((c8 ^ (rr & 15)) * 8)];
    }
}

// ---------------- fused layer v3: 64-node tile, paired-node gather, masked batches ----------------
// 512 threads = 8 waves; each wave gathers 8 nodes (4 pairs); LDS: Ts 16KB + Ws 32KB
__global__ __launch_bounds__(512, 6) void layer_fused(const unsigned* __restrict__ H2,
                                                      const unsigned* __restrict__ X02,
                                                      const float* __restrict__ dinv,
                                                      const int* __restrict__ row_ptr,
                                                      const int2* __restrict__ edges,
                                                      const __hip_bfloat16* __restrict__ WTl,
                                                      float beta,
                                                      __hip_bfloat16* __restrict__ Hout,
                                                      float* __restrict__ Zf) {
    __shared__ short Ts[64 * 128];
    __shared__ short Ws[128 * 128];
    int tid = threadIdx.x;
    int w = tid >> 6, l = tid & 63, g = l >> 4, r = l & 15;
    int row0 = blockIdx.x * 64;

    // load W tile (swizzled 16-slot XOR): 2048 uint4 over 512 threads
#pragma unroll
    for (int i = 0; i < 4; ++i) {
        int id = i * 512 + tid;
        int rr = id >> 4, slot = id & 15;
        uint4 wv = *(const uint4*)&WTl[(size_t)id * 8];
        *(uint4*)&Ws[rr * 128 + (slot ^ (rr & 15)) * 8] = wv;
    }

    // gather: wave w -> nodes row0 + w*8 .. +7, processed as 4 concurrent pairs
    unsigned* TsU = (unsigned*)Ts;
    int nb0 = row0 + w * 8;
    int ep[9];
#pragma unroll
    for (int k = 0; k < 9; ++k) ep[k] = __builtin_amdgcn_readfirstlane(row_ptr[nb0 + k]);

#pragma unroll
    for (int j = 0; j < 4; ++j) {
        int rrA = w * 8 + 2 * j, rrB = rrA + 1;
        int nA = row0 + rrA, nB = nA + 1;
        bool vA = nA < NN, vB = nB < NN;
        unsigned hsA = vA ? H2[((unsigned)nA << 6) + l] : 0u;
        unsigned hsB = vB ? H2[((unsigned)nB << 6) + l] : 0u;
        unsigned xvA = vA ? X02[((unsigned)nA << 6) + l] : 0u;
        unsigned xvB = vB ? X02[((unsigned)nB << 6) + l] : 0u;
        float dvA = vA ? dinv[nA] : 0.f, dvB = vB ? dinv[nB] : 0.f;
        float a0A = dvA * dvA * bflo(hsA), a1A = dvA * dvA * bfhi(hsA);
        float a0B = dvB * dvB * bflo(hsB), a1B = dvB * dvB * bfhi(hsB);
        int eA = ep[2 * j], e1A = ep[2 * j + 1];
        int eB = e1A, e1B = ep[2 * j + 2];
        while (eA < e1A || eB < e1B) {
            int cA = e1A - eA; cA = cA > 8 ? 8 : (cA < 0 ? 0 : cA);
            int cB = e1B - eB; cB = cB > 8 ? 8 : (cB < 0 ? 0 : cB);
            int sA[8], sB[8];
            float wA[8], wB[8];
#pragma unroll
            for (int u = 0; u < 8; ++u) {
                int2 t = edges[eA + u];
                sA[u] = (u < cA) ? t.x : 0;
                wA[u] = (u < cA) ? __int_as_float(t.y) : 0.f;
            }
#pragma unroll
            for (int u = 0; u < 8; ++u) {
                int2 t = edges[eB + u];
                sB[u] = (u < cB) ? t.x : 0;
                wB[u] = (u < cB) ? __int_as_float(t.y) : 0.f;
            }
            unsigned hvA[8], hvB[8];
#pragma unroll
            for (int u = 0; u < 8; ++u) hvA[u] = H2[((unsigned)sA[u] << 6) + l];
#pragma unroll
            for (int u = 0; u < 8; ++u) hvB[u] = H2[((unsigned)sB[u] << 6) + l];
#pragma unroll
            for (int u = 0; u < 8; ++u) {
                a0A = fmaf(wA[u], bflo(hvA[u]), a0A);
                a1A = fmaf(wA[u], bfhi(hvA[u]), a1A);
                a0B = fmaf(wB[u], bflo(hvB[u]), a0B);
                a1B = fmaf(wB[u], bfhi(hvB[u]), a1B);
            }
            eA += cA; eB += cB;
        }
        a0A = 0.9f * a0A + 0.1f * bflo(xvA);  a1A = 0.9f * a1A + 0.1f * bfhi(xvA);
        a0B = 0.9f * a0B + 0.1f * bflo(xvB);  a1B = 0.9f * a1B + 0.1f * bfhi(xvB);
        unsigned pkA = (unsigned)f2bfu(a0A) | ((unsigned)f2bfu(a1A) << 16);
        unsigned pkB = (unsigned)f2bfu(a0B) | ((unsigned)f2bfu(a1B) << 16);
        TsU[rrA * 64 + ((l >> 2) ^ (rrA & 15)) * 4 + (l & 3)] = pkA;
        TsU[rrB * 64 + ((l >> 2) ^ (rrB & 15)) * 4 + (l & 3)] = pkB;
    }
    __syncthreads();

    // MFMA phase: wave w -> node-block nb = w&3 (16 nodes), channel-group cg = w>>2 (64 ch)
    int nb = w & 3, cg = w >> 2;
    f32x4 acc[4] = {};
#pragma unroll
    for (int ks = 0; ks < 4; ++ks) {
        int rrT = nb * 16 + r;
        short8 bT = *(short8*)&Ts[rrT * 128 + ((ks * 4 + g) ^ (rrT & 15)) * 8];
        short8 aW[4];
#pragma unroll
        for (int c = 0; c < 4; ++c) {
            int rrW = (cg * 4 + c) * 16 + r;
            aW[c] = *(short8*)&Ws[rrW * 128 + ((ks * 4 + g) ^ (rrW & 15)) * 8];
        }
#pragma unroll
        for (int c = 0; c < 4; ++c)
            acc[c] = __builtin_amdgcn_mfma_f32_16x16x32_bf16(aW[c], bT, acc[c], 0, 0, 0);
    }

    // epilogue: lane holds channels (cg*4+c)*16 + g*4 .. +3 of node nb*16+r
    float omb = 1.0f - beta;
    int node = nb * 16 + r;
    int grow = row0 + node;
    if (grow < NN) {
#pragma unroll
        for (int c = 0; c < 4; ++c) {
            int c0 = (cg * 4 + c) * 16 + g * 4;
            int slotE = c0 >> 3, posE = c0 & 7;
            ushort4v tv = *(ushort4v*)&Ts[node * 128 + (slotE ^ (node & 15)) * 8 + posE];
            float o[4];
#pragma unroll
            for (int q = 0; q < 4; ++q)
                o[q] = fmaxf(omb * bf2f(tv[q]) + beta * acc[c][q], 0.f);
            if (Zf) {
                *(float4*)&Zf[(size_t)grow * HID + c0] = make_float4(o[0], o[1], o[2], o[3]);
            } else {
                ushort4v hv;
#pragma unroll
                for (int q = 0; q < 4; ++q) hv[q] = f2bfu(o[q]);
                *(ushort4v*)&Hout[(size_t)grow * HID + c0] = hv;
            }
        }
    }
}

// ---------------- final: log_softmax(z @ W_out + b_out); z already in d_out ----------------
__global__ __launch_bounds__(64) void final_kernel(const float* __restrict__ Z,
                                                   const float* __restrict__ Wout,
                                                   const float* __restrict__ bout,
                                                   float* __restrict__ lo) {
    int n = blockIdx.x;
    int c = threadIdx.x;
    float logit = bout[c];
    for (int k = 0; k < HID; ++k) {
        logit = fmaf(Z[(size_t)n * HID + k], Wout[k * C_OUT + c], logit);
    }
    float m = logit;
#pragma unroll
    for (int off = 32; off; off >>= 1) m = fmaxf(m, __shfl_xor(m, off));
    float ex = __expf(logit - m);
    float ssum = ex;
#pragma unroll
    for (int off = 32; off; off >>= 1) ssum += __shfl_xor(ssum, off);
    lo[(size_t)n * C_OUT + c] = logit - m - logf(ssum);
}

extern "C" void kernel_launch(void* const* d_in, const int* in_sizes, int n_in,
                              void* d_out, int out_size, void* d_ws, size_t ws_size,
                              hipStream_t stream) {
    const float* x = (const float*)d_in[0];
    const int* ei = (const int*)d_in[1];
    const int* src = ei;
    const int* dst = ei + NE;
    const float* W_in = (const float*)d_in[2];
    const float* b_in = (const float*)d_in[3];
    const float* W_convs = (const float*)d_in[4];
    const float* W_out = (const float*)d_in[5];
    const float* b_out = (const float*)d_in[6];
    float* out = (float*)d_out;

    char* ws = (char*)d_ws;
    float* dinv = (float*)ws;              ws += (size_t)NN * 4;
    int* row_ptr = (int*)ws;               ws += (size_t)(NN + 72) * 4;
    int* fill = (int*)ws;                  ws += (size_t)NN * 4;
    int* partial = (int*)ws;               ws += (size_t)128 * 4;
    int2* edges = (int2*)ws;               ws += (size_t)(NE + 8) * 8;
    __hip_bfloat16* WT = (__hip_bfloat16*)ws;   ws += (size_t)L_LAYERS * HID * HID * 2;
    __hip_bfloat16* WinT = (__hip_bfloat16*)ws; ws += (size_t)F_IN * HID * 2;
    __hip_bfloat16* x0b = (__hip_bfloat16*)ws;  ws += (size_t)NN * HID * 2;
    __hip_bfloat16* HbA = (__hip_bfloat16*)ws;  ws += (size_t)NN * HID * 2;
    __hip_bfloat16* HbB = (__hip_bfloat16*)ws;  ws += (size_t)NN * HID * 2;

    hipMemsetAsync(fill, 0, (size_t)NN * 4, stream);
    count_deg<<<(NE + 255) / 256, 256, 0, stream>>>(dst, fill);
    compute_dinv<<<(NN + 255) / 256, 256, 0, stream>>>(fill, dinv);
    scan1<<<SCAN_NB, 256, 0, stream>>>(fill, row_ptr, partial);
    scan2<<<1, 128, 0, stream>>>(partial);
    scan3<<<(NN + 255) / 256, 256, 0, stream>>>(row_ptr, partial);
    hipMemcpyAsync(fill, row_ptr, (size_t)NN * 4, hipMemcpyDeviceToDevice, stream);
    scatter_csr<<<(NE + 255) / 256, 256, 0, stream>>>(src, dst, dinv, fill, edges);
    prep_wt<<<80, 256, 0, stream>>>(W_convs, W_in, WT, WinT);

    int gemm_blocks = (NN + 127) / 128;
    gemm_x0_mfma<<<gemm_blocks, 256, 0, stream>>>(x, WinT, b_in, x0b);

    int layer_blocks = (NN + 63) / 64;
    float* zf = out;  // last layer writes fp32 z directly into d_out
    for (int l = 0; l < L_LAYERS; ++l) {
        const __hip_bfloat16* h_in = (l == 0) ? x0b : ((l & 1) ? HbA : HbB);
        __hip_bfloat16* h_out = (l & 1) ? HbB : HbA;
        float beta = logf(0.5f / (float)(l + 1) + 1.0f);
        bool last = (l == L_LAYERS - 1);
        layer_fused<<<layer_blocks, 512, 0, stream>>>(
            (const unsigned*)h_in, (const unsigned*)x0b, dinv, row_ptr, edges,
            WT + (size_t)l * HID * HID, beta,
            h_out, last ? zf : (float*)nullptr);
    }

    final_kernel<<<NN, 64, 0, stream>>>(zf, W_out, b_out, out + (size_t)NN * HID);
}